// Round 1
// 8496.659 us; speedup vs baseline: 1.2661x; 1.2661x over previous
//
#include <hip/hip_runtime.h>
#include <math.h>

#define NB 128
#define NITEMS 8192
#define NHID 256
#define NLAT 64
#define NEMB_ 512
#define NQ_ 4
#define LENC 4096
#define LDEC 8192
#define NROWS 524288            // NB*NLAT*LENC/64
#define VQ_NELEM 33554432.0f    // NB*NLAT*LENC

typedef unsigned short u16;
typedef __attribute__((ext_vector_type(8))) short bf16x8;
typedef __attribute__((ext_vector_type(4))) float f32x4;

__device__ __forceinline__ u16 f2b(float f){
  unsigned u = __float_as_uint(f);
  unsigned r = (u + 0x7FFFu + ((u>>16)&1u)) >> 16;
  return (u16)r;
}
__device__ __forceinline__ float b2f(u16 h){
  return __uint_as_float(((unsigned)h)<<16);
}

// ---------------------------------------------------------------- small prep
__global__ void k_zero(float* __restrict__ p, int n){
  int i = blockIdx.x*256 + threadIdx.x;
  if(i < n) p[i] = 0.f;
}

__global__ void k_gather(const int* __restrict__ uid, const float* __restrict__ mat,
                         float* __restrict__ x){
  int b = blockIdx.y;
  int i = blockIdx.x*256 + threadIdx.x;
  x[(size_t)b*NITEMS + i] = mat[(size_t)uid[b]*NITEMS + i];
}

// w[CO][CI][K] f32 -> wb[k][co][ci] bf16
__global__ void k_packw(const float* __restrict__ w, u16* __restrict__ wb,
                        int CO, int CI, int K){
  int idx = blockIdx.x*256 + threadIdx.x;
  int n = CO*CI*K;
  if(idx >= n) return;
  int k  = idx % K;
  int ci = (idx / K) % CI;
  int co = idx / (K*CI);
  wb[((size_t)k*CO + co)*CI + ci] = f2b(w[idx]);
}

// ConvTranspose w[CI=64][CO=256][4] f32 -> wb[tap][co][ci] bf16
__global__ void k_packwT(const float* __restrict__ w, u16* __restrict__ wb){
  int idx = blockIdx.x*256 + threadIdx.x;
  if(idx >= 64*256*4) return;
  int k  = idx % 4;
  int co = (idx / 4) % 256;
  int ci = idx / (4*256);
  wb[((size_t)k*256 + co)*64 + ci] = f2b(w[idx]);
}

// split-precision codebook for MFMA distance GEMM:
// s = -2*cb ; cbh = bf16_rne(s) ; cbl = bf16_rne(s - cbh)
__global__ void k_cbsplit(const float* __restrict__ cb, u16* __restrict__ h,
                          u16* __restrict__ l){
  int idx = blockIdx.x*256 + threadIdx.x;   // NQ*NEMB*64 total
  float v = -2.0f*cb[idx];
  u16 hh = f2b(v);
  h[idx] = hh;
  l[idx] = f2b(v - b2f(hh));
}

__global__ void k_cbnorm(const float* __restrict__ cb, float* __restrict__ cb2){
  int idx = blockIdx.x*256 + threadIdx.x;
  if(idx >= NQ_*NEMB_) return;
  const float* p = cb + (size_t)idx*64;
  float s = 0.f;
  #pragma unroll
  for(int d=0; d<64; d++) s = fmaf(p[d], p[d], s);
  cb2[idx] = s;
}

// --------------------------- encoder first conv (C_in=1, K=4, s=2), bf16 ch-last
// out[b][l][co] = relu(bias[co] + sum_k w[co*4+k]*x[2l-1+k])
__global__ __launch_bounds__(256) void k_enc0(
    const float* __restrict__ x, const float* __restrict__ w,
    const float* __restrict__ bias, u16* __restrict__ out){
  const int co = threadIdx.x;
  const int b  = blockIdx.y;
  const int l0 = blockIdx.x*16;
  const float* xr = x + (size_t)b*NITEMS;
  float4 wv = *(const float4*)&w[co*4];
  float bv = bias[co];
  for(int dl=0; dl<16; dl++){
    int l = l0 + dl;
    int i0 = 2*l - 1;
    float x0 = (i0 >= 0) ? xr[i0] : 0.f;
    float x1 = xr[i0+1];
    float x2 = xr[i0+2];
    float x3 = (i0+3 < NITEMS) ? xr[i0+3] : 0.f;
    float acc = bv;
    acc = fmaf(wv.x, x0, acc); acc = fmaf(wv.y, x1, acc);
    acc = fmaf(wv.z, x2, acc); acc = fmaf(wv.w, x3, acc);
    out[((size_t)(b*LENC + l))*NHID + co] = f2b(fmaxf(acc, 0.f));
  }
}

// --------------------------------------------- generic implicit-GEMM conv (MFMA)
// in:  bf16 ch-last [b][L][CIN]
// wb:  bf16 [KK][COUT][CIN]  (tap-major)
// out: bf16 ch-last [b][L][COUT]   (CHF=0)
//      f32 ch-first [b][COUT][L]   (CHF=1, for z_e)
// RES: out += res (bf16 ch-last), pre-relu.
// block = 4 waves; wave grid WM x WN; wave computes 64co x 64l (4x4 16x16 tiles)
#define LP 40   // LDS row stride in bf16 (80B: 16B-aligned, odd bank groups)
template<int CIN, int COUT, int KK, int WM, int WN, int RELU, int RES, int CHF>
__global__ __launch_bounds__(256) void k_cgemm(
    const u16* __restrict__ in, const u16* __restrict__ wb,
    const float* __restrict__ bias, const u16* __restrict__ res,
    void* __restrict__ outv, int L){
  constexpr int CO_T = WM*64;
  constexpr int LT   = WN*64;
  constexpr int PAD  = (KK-1)/2;
  constexpr int RXS  = LT + KK - 1;
  __shared__ __align__(16) u16 sx[RXS][LP];
  __shared__ __align__(16) u16 sw[KK][CO_T][LP];

  const int tid = threadIdx.x;
  const int bb  = blockIdx.z;
  const int co0 = blockIdx.y*CO_T;
  const int l0  = blockIdx.x*LT;
  const int wave = tid>>6, lane = tid&63;
  const int wm = wave % WM, wn = wave / WM;
  const int quad = lane>>4, l16 = lane&15;

  f32x4 acc[4][4];
  #pragma unroll
  for(int m=0;m<4;m++)
    #pragma unroll
    for(int n=0;n<4;n++) acc[m][n] = (f32x4){0.f,0.f,0.f,0.f};

  for(int cib=0; cib<CIN; cib+=32){
    // stage activations: rows l0-PAD .. l0-PAD+RXS-1, 32 ci each (4x16B chunks)
    for(int s=tid; s<RXS*4; s+=256){
      int row = s>>2, ch = s&3;
      int l = l0 - PAD + row;
      int4 v;
      if(l >= 0 && l < L)
        v = *(const int4*)(in + ((size_t)(bb*L + l))*CIN + cib + ch*8);
      else
        v = make_int4(0,0,0,0);
      *(int4*)&sx[row][ch*8] = v;
    }
    // stage weights: [kk][co-tile][32ci]
    for(int s=tid; s<KK*CO_T*4; s+=256){
      int row = s>>2, ch = s&3;
      int kk = row / CO_T, cr = row % CO_T;
      int4 v = *(const int4*)(wb + ((size_t)(kk*COUT + co0 + cr))*CIN + cib + ch*8);
      *(int4*)&sw[kk][cr][ch*8] = v;
    }
    __syncthreads();
    #pragma unroll
    for(int kk=0; kk<KK; kk++){
      bf16x8 af[4];
      #pragma unroll
      for(int m=0;m<4;m++)
        af[m] = *(const bf16x8*)&sw[kk][wm*64 + m*16 + l16][quad*8];
      #pragma unroll
      for(int n=0;n<4;n++){
        bf16x8 bf = *(const bf16x8*)&sx[wn*64 + n*16 + l16 + kk][quad*8];
        #pragma unroll
        for(int m=0;m<4;m++)
          acc[m][n] = __builtin_amdgcn_mfma_f32_16x16x32_bf16(af[m], bf, acc[m][n], 0,0,0);
      }
    }
    __syncthreads();
  }

  // epilogue
  #pragma unroll
  for(int m=0;m<4;m++){
    int co4 = co0 + wm*64 + m*16 + quad*4;
    float4 bv = *(const float4*)&bias[co4];
    #pragma unroll
    for(int n=0;n<4;n++){
      int l = l0 + wn*64 + n*16 + l16;
      float v0 = acc[m][n][0] + bv.x;
      float v1 = acc[m][n][1] + bv.y;
      float v2 = acc[m][n][2] + bv.z;
      float v3 = acc[m][n][3] + bv.w;
      if(RES){
        ushort4 rv = *(const ushort4*)(res + ((size_t)(bb*L + l))*COUT + co4);
        v0 += b2f(rv.x); v1 += b2f(rv.y); v2 += b2f(rv.z); v3 += b2f(rv.w);
      }
      if(RELU){
        v0 = fmaxf(v0,0.f); v1 = fmaxf(v1,0.f); v2 = fmaxf(v2,0.f); v3 = fmaxf(v3,0.f);
      }
      if(CHF){
        float* of = (float*)outv;
        of[((size_t)(bb*COUT + co4+0))*L + l] = v0;
        of[((size_t)(bb*COUT + co4+1))*L + l] = v1;
        of[((size_t)(bb*COUT + co4+2))*L + l] = v2;
        of[((size_t)(bb*COUT + co4+3))*L + l] = v3;
      }else{
        u16* ob = (u16*)outv;
        ushort4 o;
        o.x = f2b(v0); o.y = f2b(v1); o.z = f2b(v2); o.w = f2b(v3);
        *(ushort4*)(ob + ((size_t)(bb*L + l))*COUT + co4) = o;
      }
    }
  }
}

// --------------------------------------------------- residual-VQ (all 4 stages)
// MFMA distance GEMM, split-bf16 precision (hi/lo pairs for both operands):
//   dot(r,-2c) = Ah.Bh + Ah.Bl + Al.Bh  (AlBl term ~2^-18, dropped)
// rows-as-columns: one wave owns 32 rows (2 B-tiles of 16).  A = codes (16/tile,
// 32 tiles).  dist = |c|^2 + acc.  Argmin with first-index tie-break; residual
// kept as hi/lo bf16 register frags; z_q accumulated exactly in f32 as the sum
// of selected codebook rows (matches reference's stage-wise f32 sum).
__global__ __launch_bounds__(256) void k_vq(
    const float* __restrict__ z_e, const float* __restrict__ cb,
    const u16* __restrict__ cbh, const u16* __restrict__ cbl,
    const float* __restrict__ cb2,
    float* __restrict__ z_q, float* __restrict__ loss, int* __restrict__ counts){
  __shared__ int hist[NQ_][NEMB_];
  __shared__ float sloss[NQ_];
  const int tid = threadIdx.x;
  for(int i=tid;i<NQ_*NEMB_;i+=256) (&hist[0][0])[i]=0;
  if(tid < NQ_) sloss[tid] = 0.f;
  __syncthreads();

  const int lane = tid & 63, wave = tid >> 6;
  const int quad = lane >> 4, l16 = lane & 15;
  const size_t row0 = (size_t)blockIdx.x*128 + (size_t)wave*32;

  // residual hi/lo B-frags [bt][kstep], z_q f32 accumulator
  bf16x8 vbh[2][2], vbl[2][2];
  float qa[2][2][8];
  #pragma unroll
  for(int bt=0;bt<2;bt++){
    #pragma unroll
    for(int ks=0;ks<2;ks++){
      const float* zp = z_e + (row0 + bt*16 + l16)*64 + ks*32 + quad*8;
      float4 v0 = *(const float4*)zp;
      float4 v1 = *(const float4*)(zp+4);
      float f[8] = {v0.x,v0.y,v0.z,v0.w,v1.x,v1.y,v1.z,v1.w};
      #pragma unroll
      for(int j=0;j<8;j++){
        u16 h = f2b(f[j]);
        vbh[bt][ks][j] = (short)h;
        vbl[bt][ks][j] = (short)f2b(f[j] - b2f(h));
        qa[bt][ks][j] = 0.f;
      }
    }
  }

  #pragma unroll 1
  for(int q=0;q<NQ_;q++){
    const u16* Ah = cbh + (size_t)q*NEMB_*64 + (size_t)l16*64 + quad*8;
    const u16* Al = cbl + (size_t)q*NEMB_*64 + (size_t)l16*64 + quad*8;
    const float* c2q = cb2 + q*NEMB_;

    // |r|^2 partial over this lane's 16 dims per row (reduced across quads below)
    float rq0 = 0.f, rq1 = 0.f;
    #pragma unroll
    for(int ks=0;ks<2;ks++)
      #pragma unroll
      for(int j=0;j<8;j++){
        float r0 = b2f((u16)vbh[0][ks][j]) + b2f((u16)vbl[0][ks][j]);
        float r1 = b2f((u16)vbh[1][ks][j]) + b2f((u16)vbl[1][ks][j]);
        rq0 = fmaf(r0,r0,rq0); rq1 = fmaf(r1,r1,rq1);
      }

    float best0 = 3.0e38f, best1 = 3.0e38f;
    int bi0 = 0, bi1 = 0;

    // A-frag double-buffer (one tile lookahead hides L2 latency under MFMA)
    bf16x8 cah0 = *(const bf16x8*)(Ah);
    bf16x8 cah1 = *(const bf16x8*)(Ah + 32);
    bf16x8 cal0 = *(const bf16x8*)(Al);
    bf16x8 cal1 = *(const bf16x8*)(Al + 32);
    #pragma unroll 1
    for(int t=0;t<32;t++){
      int tn = (t < 31) ? (t+1) : 31;
      const u16* nh = Ah + (size_t)tn*1024;   // 16 codes * 64 dims
      const u16* nl = Al + (size_t)tn*1024;
      bf16x8 nah0 = *(const bf16x8*)(nh);
      bf16x8 nah1 = *(const bf16x8*)(nh + 32);
      bf16x8 nal0 = *(const bf16x8*)(nl);
      bf16x8 nal1 = *(const bf16x8*)(nl + 32);

      f32x4 acc0 = (f32x4){0.f,0.f,0.f,0.f};
      f32x4 acc1 = (f32x4){0.f,0.f,0.f,0.f};
      acc0 = __builtin_amdgcn_mfma_f32_16x16x32_bf16(cah0, vbh[0][0], acc0, 0,0,0);
      acc1 = __builtin_amdgcn_mfma_f32_16x16x32_bf16(cah0, vbh[1][0], acc1, 0,0,0);
      acc0 = __builtin_amdgcn_mfma_f32_16x16x32_bf16(cah0, vbl[0][0], acc0, 0,0,0);
      acc1 = __builtin_amdgcn_mfma_f32_16x16x32_bf16(cah0, vbl[1][0], acc1, 0,0,0);
      acc0 = __builtin_amdgcn_mfma_f32_16x16x32_bf16(cal0, vbh[0][0], acc0, 0,0,0);
      acc1 = __builtin_amdgcn_mfma_f32_16x16x32_bf16(cal0, vbh[1][0], acc1, 0,0,0);
      acc0 = __builtin_amdgcn_mfma_f32_16x16x32_bf16(cah1, vbh[0][1], acc0, 0,0,0);
      acc1 = __builtin_amdgcn_mfma_f32_16x16x32_bf16(cah1, vbh[1][1], acc1, 0,0,0);
      acc0 = __builtin_amdgcn_mfma_f32_16x16x32_bf16(cah1, vbl[0][1], acc0, 0,0,0);
      acc1 = __builtin_amdgcn_mfma_f32_16x16x32_bf16(cah1, vbl[1][1], acc1, 0,0,0);
      acc0 = __builtin_amdgcn_mfma_f32_16x16x32_bf16(cal1, vbh[0][1], acc0, 0,0,0);
      acc1 = __builtin_amdgcn_mfma_f32_16x16x32_bf16(cal1, vbh[1][1], acc1, 0,0,0);

      float4 c2v = *(const float4*)(c2q + t*16 + quad*4);
      float c2a[4] = {c2v.x, c2v.y, c2v.z, c2v.w};
      #pragma unroll
      for(int i=0;i<4;i++){
        int code = t*16 + quad*4 + i;          // ascending per lane: strict <
        float d0 = acc0[i] + c2a[i];           //  keeps the first (lowest) index
        float d1 = acc1[i] + c2a[i];
        if(d0 < best0){ best0 = d0; bi0 = code; }
        if(d1 < best1){ best1 = d1; bi1 = code; }
      }
      cah0 = nah0; cah1 = nah1; cal0 = nal0; cal1 = nal1;
    }

    // cross-quad reduce: argmin (index tie-break) + |r|^2 sum
    #pragma unroll
    for(int off=16; off<=32; off<<=1){
      float ob0 = __shfl_xor(best0, off); int oi0 = __shfl_xor(bi0, off);
      float ob1 = __shfl_xor(best1, off); int oi1 = __shfl_xor(bi1, off);
      if(ob0 < best0 || (ob0 == best0 && oi0 < bi0)){ best0 = ob0; bi0 = oi0; }
      if(ob1 < best1 || (ob1 == best1 && oi1 < bi1)){ best1 = ob1; bi1 = oi1; }
      rq0 += __shfl_xor(rq0, off);
      rq1 += __shfl_xor(rq1, off);
    }

    // loss: sum over rows of |r|^2 + (|c|^2 - 2 r.c)_best
    float v = (rq0 + best0) + (rq1 + best1);
    #pragma unroll
    for(int off=1; off<=8; off<<=1) v += __shfl_xor(v, off);
    if(lane == 0) atomicAdd(&sloss[q], v);
    if(quad == 0){
      atomicAdd(&hist[q][bi0], 1);
      atomicAdd(&hist[q][bi1], 1);
    }

    // residual -= chosen code; re-split hi/lo; z_q += chosen code (exact f32)
    #pragma unroll
    for(int bt=0;bt<2;bt++){
      int bi = bt ? bi1 : bi0;
      const float* cp = cb + ((size_t)q*NEMB_ + bi)*64 + quad*8;
      #pragma unroll
      for(int ks=0;ks<2;ks++){
        float4 c0 = *(const float4*)(cp + ks*32);
        float4 c1 = *(const float4*)(cp + ks*32 + 4);
        float cf[8] = {c0.x,c0.y,c0.z,c0.w,c1.x,c1.y,c1.z,c1.w};
        #pragma unroll
        for(int j=0;j<8;j++){
          float r = b2f((u16)vbh[bt][ks][j]) + b2f((u16)vbl[bt][ks][j]) - cf[j];
          u16 h = f2b(r);
          vbh[bt][ks][j] = (short)h;
          vbl[bt][ks][j] = (short)f2b(r - b2f(h));
          qa[bt][ks][j] += cf[j];
        }
      }
    }
  }

  // write z_q = sum of selected codebook rows
  #pragma unroll
  for(int bt=0;bt<2;bt++)
    #pragma unroll
    for(int ks=0;ks<2;ks++){
      float* zp = z_q + (row0 + bt*16 + l16)*64 + ks*32 + quad*8;
      float4 w0 = {qa[bt][ks][0], qa[bt][ks][1], qa[bt][ks][2], qa[bt][ks][3]};
      float4 w1 = {qa[bt][ks][4], qa[bt][ks][5], qa[bt][ks][6], qa[bt][ks][7]};
      *(float4*)zp = w0;
      *(float4*)(zp+4) = w1;
    }

  __syncthreads();
  if(tid < NQ_) atomicAdd(&loss[tid], sloss[tid]);
  for(int i=tid;i<NQ_*NEMB_;i+=256){
    int v = (&hist[0][0])[i];
    if(v) atomicAdd(&counts[i], v);
  }
}

// -------------------- ConvTranspose1d K=4 s=2 p=1 (64->256) + relu, MFMA
// z_q: f32 ch-first [b][64][4096]; out: bf16 ch-last [b][8192][256]
// even j=2t: sum_ci w[ci,co,1]*x[t] + w[ci,co,3]*x[t-1]
// odd  j=2t+1: sum_ci w[ci,co,2]*x[t] + w[ci,co,0]*x[t+1]
__global__ __launch_bounds__(256) void k_convT(
    const float* __restrict__ zq, const u16* __restrict__ wb4,
    const float* __restrict__ bias, u16* __restrict__ out){
  __shared__ __align__(16) u16 sxT[66][LP];
  __shared__ __align__(16) u16 sw4[4][128][LP];
  const int tid = threadIdx.x;
  const int bb  = blockIdx.z;
  const int co0 = blockIdx.y*128;
  const int t0  = blockIdx.x*64;
  const int wave = tid>>6, lane = tid&63;
  const int wm = wave & 1, wn = wave >> 1;
  const int quad = lane>>4, l16 = lane&15;

  f32x4 ae[4][2], ao[4][2];
  #pragma unroll
  for(int m=0;m<4;m++)
    #pragma unroll
    for(int n=0;n<2;n++){ ae[m][n]=(f32x4){0,0,0,0}; ao[m][n]=(f32x4){0,0,0,0}; }

  for(int cib=0; cib<NLAT; cib+=32){
    // stage x^T: rows t0-1..t0+64, 32 ci (fp32 -> bf16, transpose)
    for(int s=tid; s<66*32; s+=256){
      int ci = s/66, tt = s%66;
      int t = t0 - 1 + tt;
      float v = 0.f;
      if(t >= 0 && t < LENC) v = zq[((size_t)(bb*NLAT + cib + ci))*LENC + t];
      sxT[tt][ci] = f2b(v);
    }
    // stage weights: 4 taps x 128 co x 32 ci
    for(int s=tid; s<4*128*4; s+=256){
      int row = s>>2, ch = s&3;
      int tap = row>>7, cr = row&127;
      int4 v = *(const int4*)(wb4 + ((size_t)(tap*NHID + co0 + cr))*NLAT + cib + ch*8);
      *(int4*)&sw4[tap][cr][ch*8] = v;
    }
    __syncthreads();
    #pragma unroll
    for(int m=0;m<4;m++){
      int crow = wm*64 + m*16 + l16;
      bf16x8 a0 = *(const bf16x8*)&sw4[0][crow][quad*8];
      bf16x8 a1 = *(const bf16x8*)&sw4[1][crow][quad*8];
      bf16x8 a2 = *(const bf16x8*)&sw4[2][crow][quad*8];
      bf16x8 a3 = *(const bf16x8*)&sw4[3][crow][quad*8];
      #pragma unroll
      for(int n=0;n<2;n++){
        int off = wn*32 + n*16 + l16;
        bf16x8 bm = *(const bf16x8*)&sxT[off  ][quad*8];   // x[t-1]
        bf16x8 b0 = *(const bf16x8*)&sxT[off+1][quad*8];   // x[t]
        bf16x8 bp = *(const bf16x8*)&sxT[off+2][quad*8];   // x[t+1]
        ae[m][n] = __builtin_amdgcn_mfma_f32_16x16x32_bf16(a1, b0, ae[m][n], 0,0,0);
        ae[m][n] = __builtin_amdgcn_mfma_f32_16x16x32_bf16(a3, bm, ae[m][n], 0,0,0);
        ao[m][n] = __builtin_amdgcn_mfma_f32_16x16x32_bf16(a2, b0, ao[m][n], 0,0,0);
        ao[m][n] = __builtin_amdgcn_mfma_f32_16x16x32_bf16(a0, bp, ao[m][n], 0,0,0);
      }
    }
    __syncthreads();
  }

  #pragma unroll
  for(int m=0;m<4;m++){
    int co4 = co0 + wm*64 + m*16 + quad*4;
    float4 bv = *(const float4*)&bias[co4];
    #pragma unroll
    for(int n=0;n<2;n++){
      int t = t0 + wn*32 + n*16 + l16;
      int je = 2*t, jo = 2*t+1;
      ushort4 oe, oo;
      oe.x = f2b(fmaxf(ae[m][n][0]+bv.x, 0.f));
      oe.y = f2b(fmaxf(ae[m][n][1]+bv.y, 0.f));
      oe.z = f2b(fmaxf(ae[m][n][2]+bv.z, 0.f));
      oe.w = f2b(fmaxf(ae[m][n][3]+bv.w, 0.f));
      oo.x = f2b(fmaxf(ao[m][n][0]+bv.x, 0.f));
      oo.y = f2b(fmaxf(ao[m][n][1]+bv.y, 0.f));
      oo.z = f2b(fmaxf(ao[m][n][2]+bv.z, 0.f));
      oo.w = f2b(fmaxf(ao[m][n][3]+bv.w, 0.f));
      *(ushort4*)(out + ((size_t)(bb*LDEC + je))*NHID + co4) = oe;
      *(ushort4*)(out + ((size_t)(bb*LDEC + jo))*NHID + co4) = oo;
    }
  }
}

// -------------------- final ConvTranspose K=3 s=1 p=1 (256->1), f32 out
// dvec[b,j] = b0 + sum_ci( w[ci*3+2]*d[j-1] + w[ci*3+1]*d[j] + w[ci*3+0]*d[j+1] )
__global__ __launch_bounds__(256) void k_finalT(
    const u16* __restrict__ in, const float* __restrict__ w,
    const float* __restrict__ bias, float* __restrict__ out){
  __shared__ u16 sd[66][258];
  __shared__ float red[4][64];
  const int tid = threadIdx.x;
  const int j0 = blockIdx.x*64;
  const int bb = blockIdx.y;
  // stage rows j0-1 .. j0+64 (256 ci each)
  for(int s=tid; s<66*32; s+=256){
    int row = s>>5, ch = s&31;
    int l = j0 - 1 + row;
    int4 v = make_int4(0,0,0,0);
    if(l >= 0 && l < LDEC)
      v = *(const int4*)(in + ((size_t)(bb*LDEC + l))*NHID + ch*8);
    // scalar int writes (row stride 258 u16 = 516B, not 16B aligned)
    int* dst = (int*)&sd[row][ch*8];
    dst[0]=v.x; dst[1]=v.y; dst[2]=v.z; dst[3]=v.w;
  }
  __syncthreads();
  const int jl = tid & 63;
  const int part = tid >> 6;   // wave-uniform
  float acc = 0.f;
  for(int ci=0; ci<64; ci++){
    int cg = part*64 + ci;
    float w0 = w[cg*3+2], w1 = w[cg*3+1], w2 = w[cg*3+0];
    acc = fmaf(w0, b2f(sd[jl  ][cg]), acc);
    acc = fmaf(w1, b2f(sd[jl+1][cg]), acc);
    acc = fmaf(w2, b2f(sd[jl+2][cg]), acc);
  }
  red[part][jl] = acc;
  __syncthreads();
  if(tid < 64)
    out[(size_t)bb*NITEMS + j0 + tid] =
      bias[0] + red[0][tid] + red[1][tid] + red[2][tid] + red[3][tid];
}

// ------------------------------------ out projection: recon = dvec @ W^T + b
__global__ __launch_bounds__(256) void k_outproj(
    const float* __restrict__ dvec, const float* __restrict__ Wm,
    const float* __restrict__ bias, float* __restrict__ out){
  __shared__ float s_d[32][129];   // [m][b]
  __shared__ float s_w[32][65];    // [m][n]
  const int tid = threadIdx.x;
  const int n_base = blockIdx.x*64;
  const int n_grp = tid>>4;        // 0..15
  const int b_grp = tid&15;        // 0..15
  float acc[4][8];
  #pragma unroll
  for(int k=0;k<4;k++)
    #pragma unroll
    for(int j=0;j<8;j++) acc[k][j]=0.f;

  const int mloc = tid&31;
  const int half = tid>>5;         // 0..7
  for(int m0=0; m0<NITEMS; m0+=32){
    #pragma unroll
    for(int r=0;r<16;r++){
      int bbv = half + r*8;
      s_d[mloc][bbv] = dvec[(size_t)bbv*NITEMS + m0 + mloc];
    }
    #pragma unroll
    for(int r=0;r<8;r++){
      int nn = half + r*8;
      s_w[mloc][nn] = Wm[(size_t)(n_base+nn)*NITEMS + m0 + mloc];
    }
    __syncthreads();
    for(int m=0;m<32;m++){
      float wv[4], dv[8];
      #pragma unroll
      for(int k=0;k<4;k++) wv[k]=s_w[m][n_grp+16*k];
      #pragma unroll
      for(int j=0;j<8;j++) dv[j]=s_d[m][b_grp+16*j];
      #pragma unroll
      for(int k=0;k<4;k++)
        #pragma unroll
        for(int j=0;j<8;j++)
          acc[k][j]=fmaf(wv[k],dv[j],acc[k][j]);
    }
    __syncthreads();
  }
  #pragma unroll
  for(int k=0;k<4;k++){
    int n = n_base + n_grp + 16*k;
    float bv = bias[n];
    #pragma unroll
    for(int j=0;j<8;j++){
      int bbv = b_grp + 16*j;
      out[(size_t)bbv*NITEMS + n] = acc[k][j] + bv;
    }
  }
}

// ------------------------------------------------- finalize scalars
__global__ void k_finalize(const float* __restrict__ loss, const int* __restrict__ counts,
                           float* __restrict__ out){
  __shared__ float sh[512];
  const int tid = threadIdx.x;
  float perp_sum = 0.f;
  for(int q=0;q<NQ_;q++){
    float avg = (float)counts[q*NEMB_+tid] / (float)NROWS;
    sh[tid] = avg*logf(avg + 1e-10f);
    __syncthreads();
    for(int s=256;s>0;s>>=1){ if(tid<s) sh[tid]+=sh[tid+s]; __syncthreads(); }
    if(tid==0) perp_sum += expf(-sh[0]);
    __syncthreads();
  }
  if(tid==0){
    float vl = 0.f;
    for(int q=0;q<NQ_;q++) vl += 1.25f*loss[q]/VQ_NELEM;
    out[0] = vl;
    out[1] = perp_sum/(float)NQ_;
  }
}

// =================================================================== launcher
extern "C" void kernel_launch(void* const* d_in, const int* in_sizes, int n_in,
                              void* d_out, int out_size, void* d_ws, size_t ws_size,
                              hipStream_t stream){
  (void)in_sizes; (void)n_in; (void)out_size;
  const int*   uid   = (const int*)d_in[0];
  const float* mat   = (const float*)d_in[1];
  const float* ec_w  = (const float*)d_in[2];
  const float* ec_b  = (const float*)d_in[3];
  const float* er_w1 = (const float*)d_in[4];
  const float* er_b1 = (const float*)d_in[5];
  const float* er_w2 = (const float*)d_in[6];
  const float* er_b2 = (const float*)d_in[7];
  const float* ef_w  = (const float*)d_in[8];
  const float* ef_b  = (const float*)d_in[9];
  const float* cb    = (const float*)d_in[10];
  const float* dt_w  = (const float*)d_in[11];
  const float* dt_b  = (const float*)d_in[12];
  const float* dr_w1 = (const float*)d_in[13];
  const float* dr_b1 = (const float*)d_in[14];
  const float* dr_w2 = (const float*)d_in[15];
  const float* dr_b2 = (const float*)d_in[16];
  const float* df_w  = (const float*)d_in[17];
  const float* df_b  = (const float*)d_in[18];
  const float* op_w  = (const float*)d_in[19];
  const float* op_b  = (const float*)d_in[20];
  float* outp = (float*)d_out;

  // ---------------- workspace: fixed region, then chunk buffers
  float* W = (float*)d_ws;
  size_t o = 0;
  float* xg    = W + o; o += (size_t)NB*NITEMS;
  float* dvec  = W + o; o += (size_t)NB*NITEMS;
  u16* wb3e0 = (u16*)(W + o); o += 3*NHID*NHID/2;
  u16* wb3e1 = (u16*)(W + o); o += 3*NHID*NHID/2;
  u16* wb3d0 = (u16*)(W + o); o += 3*NHID*NHID/2;
  u16* wb3d1 = (u16*)(W + o); o += 3*NHID*NHID/2;
  u16* wbF   = (u16*)(W + o); o += 3*NLAT*NHID/2;
  u16* wb1e0 = (u16*)(W + o); o += NHID*NHID/2;
  u16* wb1e1 = (u16*)(W + o); o += NHID*NHID/2;
  u16* wb1d0 = (u16*)(W + o); o += NHID*NHID/2;
  u16* wb1d1 = (u16*)(W + o); o += NHID*NHID/2;
  u16* wbT   = (u16*)(W + o); o += 4*NLAT*NHID/2;
  u16* cbh   = (u16*)(W + o); o += (size_t)NQ_*NEMB_*64/2;
  u16* cbl   = (u16*)(W + o); o += (size_t)NQ_*NEMB_*64/2;
  float* cb2   = W + o; o += NQ_*NEMB_;
  float* lossb = W + o; o += 4;
  int*   counts= (int*)(W + o); o += NQ_*NEMB_;
  const size_t fixedF = o;

  // chunk buffers: two bf16 act buffers of CB*LDEC*NHID u16 each
  const size_t perBF = (size_t)LDEC*NHID/2;     // floats per batch elem per buffer
  size_t availF = ws_size/sizeof(float) > fixedF ? ws_size/sizeof(float) - fixedF : 0;
  int CB = 128;
  while(CB > 1 && (size_t)CB*2*perBF > availF) CB >>= 1;

  k_zero<<<(4 + NQ_*NEMB_ + 255)/256,256,0,stream>>>(lossb, 4 + NQ_*NEMB_);

  // weight packs (fp32 -> bf16, tap-major [k][co][ci])
  k_packw<<<(3*NHID*NHID+255)/256,256,0,stream>>>(er_w1,             wb3e0, NHID, NHID, 3);
  k_packw<<<(3*NHID*NHID+255)/256,256,0,stream>>>(er_w1+3*NHID*NHID, wb3e1, NHID, NHID, 3);
  k_packw<<<(3*NHID*NHID+255)/256,256,0,stream>>>(dr_w1,             wb3d0, NHID, NHID, 3);
  k_packw<<<(3*NHID*NHID+255)/256,256,0,stream>>>(dr_w1+3*NHID*NHID, wb3d1, NHID, NHID, 3);
  k_packw<<<(3*NLAT*NHID+255)/256,256,0,stream>>>(ef_w,              wbF,   NLAT, NHID, 3);
  k_packw<<<(NHID*NHID+255)/256,256,0,stream>>>(er_w2,               wb1e0, NHID, NHID, 1);
  k_packw<<<(NHID*NHID+255)/256,256,0,stream>>>(er_w2+NHID*NHID,     wb1e1, NHID, NHID, 1);
  k_packw<<<(NHID*NHID+255)/256,256,0,stream>>>(dr_w2,               wb1d0, NHID, NHID, 1);
  k_packw<<<(NHID*NHID+255)/256,256,0,stream>>>(dr_w2+NHID*NHID,     wb1d1, NHID, NHID, 1);
  k_packwT<<<(4*NLAT*NHID+255)/256,256,0,stream>>>(dt_w, wbT);
  k_cbsplit<<<(NQ_*NEMB_*64)/256,256,0,stream>>>(cb, cbh, cbl);
  k_cbnorm<<<(NQ_*NEMB_+255)/256,256,0,stream>>>(cb, cb2);

  k_gather<<<dim3(NITEMS/256, NB),256,0,stream>>>(uid, mat, xg);

  u16* D0b = (u16*)(W + fixedF);
  u16* D1b = D0b + (size_t)CB*LDEC*NHID;

  for(int c0 = 0; c0 < NB; c0 += CB){
    u16* E0 = D0b;                                  // [CB][4096][256] bf16
    u16* E1 = D0b + (size_t)CB*LENC*NHID;
    float* z_e = (float*)D1b;                       // [CB][64][4096] f32
    float* z_q = z_e + (size_t)CB*NLAT*LENC;
    const float* xgc = xg + (size_t)c0*NITEMS;
    float* dvc = dvec + (size_t)c0*NITEMS;

    // ---- encoder
    k_enc0<<<dim3(LENC/16, CB),256,0,stream>>>(xgc, ec_w, ec_b, E0);
    k_cgemm<256,256,3,2,2,1,0,0><<<dim3(LENC/128, 2, CB),256,0,stream>>>(E0, wb3e0, er_b1,      nullptr, E1, LENC);
    k_cgemm<256,256,1,2,2,1,1,0><<<dim3(LENC/128, 2, CB),256,0,stream>>>(E1, wb1e0, er_b2,      E0,      E0, LENC);
    k_cgemm<256,256,3,2,2,1,0,0><<<dim3(LENC/128, 2, CB),256,0,stream>>>(E0, wb3e1, er_b1+NHID, nullptr, E1, LENC);
    k_cgemm<256,256,1,2,2,1,1,0><<<dim3(LENC/128, 2, CB),256,0,stream>>>(E1, wb1e1, er_b2+NHID, E0,      E0, LENC);
    k_cgemm<256, 64,3,1,4,0,0,1><<<dim3(LENC/256, 1, CB),256,0,stream>>>(E0, wbF,   ef_b,       nullptr, z_e, LENC);

    // ---- residual VQ (MFMA split-bf16): 128 rows/block, 32 rows/wave
    k_vq<<<CB*32,256,0,stream>>>(z_e, cb, cbh, cbl, cb2, z_q, lossb, counts);

    // ---- decoder
    k_convT<<<dim3(LENC/64, 2, CB),256,0,stream>>>(z_q, wbT, dt_b, D0b);
    k_cgemm<256,256,3,2,2,1,0,0><<<dim3(LDEC/128, 2, CB),256,0,stream>>>(D0b, wb3d0, dr_b1,      nullptr, D1b, LDEC);
    k_cgemm<256,256,1,2,2,1,1,0><<<dim3(LDEC/128, 2, CB),256,0,stream>>>(D1b, wb1d0, dr_b2,      D0b,     D0b, LDEC);
    k_cgemm<256,256,3,2,2,1,0,0><<<dim3(LDEC/128, 2, CB),256,0,stream>>>(D0b, wb3d1, dr_b1+NHID, nullptr, D1b, LDEC);
    k_cgemm<256,256,1,2,2,1,1,0><<<dim3(LDEC/128, 2, CB),256,0,stream>>>(D1b, wb1d1, dr_b2+NHID, D0b,     D0b, LDEC);
    k_finalT<<<dim3(LDEC/64, CB),256,0,stream>>>(D0b, df_w, df_b, dvc);
  }

  // ---- head + scalars
  k_outproj<<<NITEMS/64,256,0,stream>>>(dvec, op_w, op_b, outp);
  k_finalize<<<1,512,0,stream>>>(lossb, counts, outp + (size_t)NB*NITEMS);
}

// Round 2
// 6858.533 us; speedup vs baseline: 1.5685x; 1.2388x over previous
//
#include <hip/hip_runtime.h>
#include <math.h>

#define NB 128
#define NITEMS 8192
#define NHID 256
#define NLAT 64
#define NEMB_ 512
#define NQ_ 4
#define LENC 4096
#define LDEC 8192
#define NROWS 524288            // NB*NLAT*LENC/64
#define VQ_NELEM 33554432.0f    // NB*NLAT*LENC
#define KC_ 4                   // out-proj K-chunks

typedef unsigned short u16;
typedef __attribute__((ext_vector_type(8))) short bf16x8;
typedef __attribute__((ext_vector_type(4))) float f32x4;

__device__ __forceinline__ u16 f2b(float f){
  unsigned u = __float_as_uint(f);
  unsigned r = (u + 0x7FFFu + ((u>>16)&1u)) >> 16;
  return (u16)r;
}
__device__ __forceinline__ float b2f(u16 h){
  return __uint_as_float(((unsigned)h)<<16);
}

// ---------------------------------------------------------------- small prep
__global__ void k_zero(float* __restrict__ p, int n){
  int i = blockIdx.x*256 + threadIdx.x;
  if(i < n) p[i] = 0.f;
}

__global__ void k_gather(const int* __restrict__ uid, const float* __restrict__ mat,
                         float* __restrict__ x){
  int b = blockIdx.y;
  int i = blockIdx.x*256 + threadIdx.x;
  x[(size_t)b*NITEMS + i] = mat[(size_t)uid[b]*NITEMS + i];
}

// w[CO][CI][K] f32 -> wb[k][co][ci] bf16
__global__ void k_packw(const float* __restrict__ w, u16* __restrict__ wb,
                        int CO, int CI, int K){
  int idx = blockIdx.x*256 + threadIdx.x;
  int n = CO*CI*K;
  if(idx >= n) return;
  int k  = idx % K;
  int ci = (idx / K) % CI;
  int co = idx / (K*CI);
  wb[((size_t)k*CO + co)*CI + ci] = f2b(w[idx]);
}

// ConvTranspose w[CI=64][CO=256][4] f32 -> wb[tap][co][ci] bf16
__global__ void k_packwT(const float* __restrict__ w, u16* __restrict__ wb){
  int idx = blockIdx.x*256 + threadIdx.x;
  if(idx >= 64*256*4) return;
  int k  = idx % 4;
  int co = (idx / 4) % 256;
  int ci = idx / (4*256);
  wb[((size_t)k*256 + co)*64 + ci] = f2b(w[idx]);
}

// split-precision codebook for MFMA distance GEMM:
// s = -2*cb ; cbh = bf16_rne(s) ; cbl = bf16_rne(s - cbh)
__global__ void k_cbsplit(const float* __restrict__ cb, u16* __restrict__ h,
                          u16* __restrict__ l){
  int idx = blockIdx.x*256 + threadIdx.x;   // NQ*NEMB*64 total
  float v = -2.0f*cb[idx];
  u16 hh = f2b(v);
  h[idx] = hh;
  l[idx] = f2b(v - b2f(hh));
}

__global__ void k_cbnorm(const float* __restrict__ cb, float* __restrict__ cb2){
  int idx = blockIdx.x*256 + threadIdx.x;
  if(idx >= NQ_*NEMB_) return;
  const float* p = cb + (size_t)idx*64;
  float s = 0.f;
  #pragma unroll
  for(int d=0; d<64; d++) s = fmaf(p[d], p[d], s);
  cb2[idx] = s;
}

// dvec f32 [B][NITEMS] -> hi/lo bf16 (for out-proj MFMA)
__global__ void k_packdv(const float* __restrict__ d, u16* __restrict__ h,
                         u16* __restrict__ l){
  int i = blockIdx.x*256 + threadIdx.x;
  float v = d[i];
  u16 hh = f2b(v);
  h[i] = hh;
  l[i] = f2b(v - b2f(hh));
}

// --------------------------- encoder first conv (C_in=1, K=4, s=2), bf16 ch-last
// out[b][l][co] = relu(bias[co] + sum_k w[co*4+k]*x[2l-1+k])
__global__ __launch_bounds__(256) void k_enc0(
    const float* __restrict__ x, const float* __restrict__ w,
    const float* __restrict__ bias, u16* __restrict__ out){
  const int co = threadIdx.x;
  const int b  = blockIdx.y;
  const int l0 = blockIdx.x*16;
  const float* xr = x + (size_t)b*NITEMS;
  float4 wv = *(const float4*)&w[co*4];
  float bv = bias[co];
  for(int dl=0; dl<16; dl++){
    int l = l0 + dl;
    int i0 = 2*l - 1;
    float x0 = (i0 >= 0) ? xr[i0] : 0.f;
    float x1 = xr[i0+1];
    float x2 = xr[i0+2];
    float x3 = (i0+3 < NITEMS) ? xr[i0+3] : 0.f;
    float acc = bv;
    acc = fmaf(wv.x, x0, acc); acc = fmaf(wv.y, x1, acc);
    acc = fmaf(wv.z, x2, acc); acc = fmaf(wv.w, x3, acc);
    out[((size_t)(b*LENC + l))*NHID + co] = f2b(fmaxf(acc, 0.f));
  }
}

// --------------------------------------------- generic implicit-GEMM conv (MFMA)
// in:  bf16 ch-last [b][L][CIN]
// wb:  bf16 [KK][COUT][CIN]  (tap-major)
// out: bf16 ch-last [b][L][COUT]   (CHF=0)
//      f32 ch-first [b][COUT][L]   (CHF=1, for z_e)
// RES: out += res (bf16 ch-last), pre-relu.
// block = 4 waves; wave grid WM x WN; wave computes 64co x 64l (4x4 16x16 tiles)
#define LP 40   // LDS row stride in bf16 (80B: 16B-aligned, odd bank groups)
template<int CIN, int COUT, int KK, int WM, int WN, int RELU, int RES, int CHF>
__global__ __launch_bounds__(256) void k_cgemm(
    const u16* __restrict__ in, const u16* __restrict__ wb,
    const float* __restrict__ bias, const u16* __restrict__ res,
    void* __restrict__ outv, int L){
  constexpr int CO_T = WM*64;
  constexpr int LT   = WN*64;
  constexpr int PAD  = (KK-1)/2;
  constexpr int RXS  = LT + KK - 1;
  __shared__ __align__(16) u16 sx[RXS][LP];
  __shared__ __align__(16) u16 sw[KK][CO_T][LP];

  const int tid = threadIdx.x;
  const int bb  = blockIdx.z;
  const int co0 = blockIdx.y*CO_T;
  const int l0  = blockIdx.x*LT;
  const int wave = tid>>6, lane = tid&63;
  const int wm = wave % WM, wn = wave / WM;
  const int quad = lane>>4, l16 = lane&15;

  f32x4 acc[4][4];
  #pragma unroll
  for(int m=0;m<4;m++)
    #pragma unroll
    for(int n=0;n<4;n++) acc[m][n] = (f32x4){0.f,0.f,0.f,0.f};

  for(int cib=0; cib<CIN; cib+=32){
    // stage activations: rows l0-PAD .. l0-PAD+RXS-1, 32 ci each (4x16B chunks)
    for(int s=tid; s<RXS*4; s+=256){
      int row = s>>2, ch = s&3;
      int l = l0 - PAD + row;
      int4 v;
      if(l >= 0 && l < L)
        v = *(const int4*)(in + ((size_t)(bb*L + l))*CIN + cib + ch*8);
      else
        v = make_int4(0,0,0,0);
      *(int4*)&sx[row][ch*8] = v;
    }
    // stage weights: [kk][co-tile][32ci]
    for(int s=tid; s<KK*CO_T*4; s+=256){
      int row = s>>2, ch = s&3;
      int kk = row / CO_T, cr = row % CO_T;
      int4 v = *(const int4*)(wb + ((size_t)(kk*COUT + co0 + cr))*CIN + cib + ch*8);
      *(int4*)&sw[kk][cr][ch*8] = v;
    }
    __syncthreads();
    #pragma unroll
    for(int kk=0; kk<KK; kk++){
      bf16x8 af[4];
      #pragma unroll
      for(int m=0;m<4;m++)
        af[m] = *(const bf16x8*)&sw[kk][wm*64 + m*16 + l16][quad*8];
      #pragma unroll
      for(int n=0;n<4;n++){
        bf16x8 bf = *(const bf16x8*)&sx[wn*64 + n*16 + l16 + kk][quad*8];
        #pragma unroll
        for(int m=0;m<4;m++)
          acc[m][n] = __builtin_amdgcn_mfma_f32_16x16x32_bf16(af[m], bf, acc[m][n], 0,0,0);
      }
    }
    __syncthreads();
  }

  // epilogue
  #pragma unroll
  for(int m=0;m<4;m++){
    int co4 = co0 + wm*64 + m*16 + quad*4;
    float4 bv = *(const float4*)&bias[co4];
    #pragma unroll
    for(int n=0;n<4;n++){
      int l = l0 + wn*64 + n*16 + l16;
      float v0 = acc[m][n][0] + bv.x;
      float v1 = acc[m][n][1] + bv.y;
      float v2 = acc[m][n][2] + bv.z;
      float v3 = acc[m][n][3] + bv.w;
      if(RES){
        ushort4 rv = *(const ushort4*)(res + ((size_t)(bb*L + l))*COUT + co4);
        v0 += b2f(rv.x); v1 += b2f(rv.y); v2 += b2f(rv.z); v3 += b2f(rv.w);
      }
      if(RELU){
        v0 = fmaxf(v0,0.f); v1 = fmaxf(v1,0.f); v2 = fmaxf(v2,0.f); v3 = fmaxf(v3,0.f);
      }
      if(CHF){
        float* of = (float*)outv;
        of[((size_t)(bb*COUT + co4+0))*L + l] = v0;
        of[((size_t)(bb*COUT + co4+1))*L + l] = v1;
        of[((size_t)(bb*COUT + co4+2))*L + l] = v2;
        of[((size_t)(bb*COUT + co4+3))*L + l] = v3;
      }else{
        u16* ob = (u16*)outv;
        ushort4 o;
        o.x = f2b(v0); o.y = f2b(v1); o.z = f2b(v2); o.w = f2b(v3);
        *(ushort4*)(ob + ((size_t)(bb*L + l))*COUT + co4) = o;
      }
    }
  }
}

// --------------------------------------------------- residual-VQ (all 4 stages)
// MFMA distance GEMM, split-bf16 precision (hi/lo pairs for both operands):
//   dot(r,-2c) = Ah.Bh + Ah.Bl + Al.Bh  (AlBl term ~2^-18, dropped)
__global__ __launch_bounds__(256) void k_vq(
    const float* __restrict__ z_e, const float* __restrict__ cb,
    const u16* __restrict__ cbh, const u16* __restrict__ cbl,
    const float* __restrict__ cb2,
    float* __restrict__ z_q, float* __restrict__ loss, int* __restrict__ counts){
  __shared__ int hist[NQ_][NEMB_];
  __shared__ float sloss[NQ_];
  const int tid = threadIdx.x;
  for(int i=tid;i<NQ_*NEMB_;i+=256) (&hist[0][0])[i]=0;
  if(tid < NQ_) sloss[tid] = 0.f;
  __syncthreads();

  const int lane = tid & 63, wave = tid >> 6;
  const int quad = lane >> 4, l16 = lane & 15;
  const size_t row0 = (size_t)blockIdx.x*128 + (size_t)wave*32;

  // residual hi/lo B-frags [bt][kstep], z_q f32 accumulator
  bf16x8 vbh[2][2], vbl[2][2];
  float qa[2][2][8];
  #pragma unroll
  for(int bt=0;bt<2;bt++){
    #pragma unroll
    for(int ks=0;ks<2;ks++){
      const float* zp = z_e + (row0 + bt*16 + l16)*64 + ks*32 + quad*8;
      float4 v0 = *(const float4*)zp;
      float4 v1 = *(const float4*)(zp+4);
      float f[8] = {v0.x,v0.y,v0.z,v0.w,v1.x,v1.y,v1.z,v1.w};
      #pragma unroll
      for(int j=0;j<8;j++){
        u16 h = f2b(f[j]);
        vbh[bt][ks][j] = (short)h;
        vbl[bt][ks][j] = (short)f2b(f[j] - b2f(h));
        qa[bt][ks][j] = 0.f;
      }
    }
  }

  #pragma unroll 1
  for(int q=0;q<NQ_;q++){
    const u16* Ah = cbh + (size_t)q*NEMB_*64 + (size_t)l16*64 + quad*8;
    const u16* Al = cbl + (size_t)q*NEMB_*64 + (size_t)l16*64 + quad*8;
    const float* c2q = cb2 + q*NEMB_;

    // |r|^2 partial over this lane's 16 dims per row (reduced across quads below)
    float rq0 = 0.f, rq1 = 0.f;
    #pragma unroll
    for(int ks=0;ks<2;ks++)
      #pragma unroll
      for(int j=0;j<8;j++){
        float r0 = b2f((u16)vbh[0][ks][j]) + b2f((u16)vbl[0][ks][j]);
        float r1 = b2f((u16)vbh[1][ks][j]) + b2f((u16)vbl[1][ks][j]);
        rq0 = fmaf(r0,r0,rq0); rq1 = fmaf(r1,r1,rq1);
      }

    float best0 = 3.0e38f, best1 = 3.0e38f;
    int bi0 = 0, bi1 = 0;

    // A-frag double-buffer (one tile lookahead hides L2 latency under MFMA)
    bf16x8 cah0 = *(const bf16x8*)(Ah);
    bf16x8 cah1 = *(const bf16x8*)(Ah + 32);
    bf16x8 cal0 = *(const bf16x8*)(Al);
    bf16x8 cal1 = *(const bf16x8*)(Al + 32);
    #pragma unroll 1
    for(int t=0;t<32;t++){
      int tn = (t < 31) ? (t+1) : 31;
      const u16* nh = Ah + (size_t)tn*1024;   // 16 codes * 64 dims
      const u16* nl = Al + (size_t)tn*1024;
      bf16x8 nah0 = *(const bf16x8*)(nh);
      bf16x8 nah1 = *(const bf16x8*)(nh + 32);
      bf16x8 nal0 = *(const bf16x8*)(nl);
      bf16x8 nal1 = *(const bf16x8*)(nl + 32);

      f32x4 acc0 = (f32x4){0.f,0.f,0.f,0.f};
      f32x4 acc1 = (f32x4){0.f,0.f,0.f,0.f};
      acc0 = __builtin_amdgcn_mfma_f32_16x16x32_bf16(cah0, vbh[0][0], acc0, 0,0,0);
      acc1 = __builtin_amdgcn_mfma_f32_16x16x32_bf16(cah0, vbh[1][0], acc1, 0,0,0);
      acc0 = __builtin_amdgcn_mfma_f32_16x16x32_bf16(cah0, vbl[0][0], acc0, 0,0,0);
      acc1 = __builtin_amdgcn_mfma_f32_16x16x32_bf16(cah0, vbl[1][0], acc1, 0,0,0);
      acc0 = __builtin_amdgcn_mfma_f32_16x16x32_bf16(cal0, vbh[0][0], acc0, 0,0,0);
      acc1 = __builtin_amdgcn_mfma_f32_16x16x32_bf16(cal0, vbh[1][0], acc1, 0,0,0);
      acc0 = __builtin_amdgcn_mfma_f32_16x16x32_bf16(cah1, vbh[0][1], acc0, 0,0,0);
      acc1 = __builtin_amdgcn_mfma_f32_16x16x32_bf16(cah1, vbh[1][1], acc1, 0,0,0);
      acc0 = __builtin_amdgcn_mfma_f32_16x16x32_bf16(cah1, vbl[0][1], acc0, 0,0,0);
      acc1 = __builtin_amdgcn_mfma_f32_16x16x32_bf16(cah1, vbl[1][1], acc1, 0,0,0);
      acc0 = __builtin_amdgcn_mfma_f32_16x16x32_bf16(cal1, vbh[0][1], acc0, 0,0,0);
      acc1 = __builtin_amdgcn_mfma_f32_16x16x32_bf16(cal1, vbh[1][1], acc1, 0,0,0);

      float4 c2v = *(const float4*)(c2q + t*16 + quad*4);
      float c2a[4] = {c2v.x, c2v.y, c2v.z, c2v.w};
      #pragma unroll
      for(int i=0;i<4;i++){
        int code = t*16 + quad*4 + i;          // ascending per lane: strict <
        float d0 = acc0[i] + c2a[i];           //  keeps the first (lowest) index
        float d1 = acc1[i] + c2a[i];
        if(d0 < best0){ best0 = d0; bi0 = code; }
        if(d1 < best1){ best1 = d1; bi1 = code; }
      }
      cah0 = nah0; cah1 = nah1; cal0 = nal0; cal1 = nal1;
    }

    // cross-quad reduce: argmin (index tie-break) + |r|^2 sum
    #pragma unroll
    for(int off=16; off<=32; off<<=1){
      float ob0 = __shfl_xor(best0, off); int oi0 = __shfl_xor(bi0, off);
      float ob1 = __shfl_xor(best1, off); int oi1 = __shfl_xor(bi1, off);
      if(ob0 < best0 || (ob0 == best0 && oi0 < bi0)){ best0 = ob0; bi0 = oi0; }
      if(ob1 < best1 || (ob1 == best1 && oi1 < bi1)){ best1 = ob1; bi1 = oi1; }
      rq0 += __shfl_xor(rq0, off);
      rq1 += __shfl_xor(rq1, off);
    }

    // loss: sum over rows of |r|^2 + (|c|^2 - 2 r.c)_best
    float v = (rq0 + best0) + (rq1 + best1);
    #pragma unroll
    for(int off=1; off<=8; off<<=1) v += __shfl_xor(v, off);
    if(lane == 0) atomicAdd(&sloss[q], v);
    if(quad == 0){
      atomicAdd(&hist[q][bi0], 1);
      atomicAdd(&hist[q][bi1], 1);
    }

    // residual -= chosen code; re-split hi/lo; z_q += chosen code (exact f32)
    #pragma unroll
    for(int bt=0;bt<2;bt++){
      int bi = bt ? bi1 : bi0;
      const float* cp = cb + ((size_t)q*NEMB_ + bi)*64 + quad*8;
      #pragma unroll
      for(int ks=0;ks<2;ks++){
        float4 c0 = *(const float4*)(cp + ks*32);
        float4 c1 = *(const float4*)(cp + ks*32 + 4);
        float cf[8] = {c0.x,c0.y,c0.z,c0.w,c1.x,c1.y,c1.z,c1.w};
        #pragma unroll
        for(int j=0;j<8;j++){
          float r = b2f((u16)vbh[bt][ks][j]) + b2f((u16)vbl[bt][ks][j]) - cf[j];
          u16 h = f2b(r);
          vbh[bt][ks][j] = (short)h;
          vbl[bt][ks][j] = (short)f2b(r - b2f(h));
          qa[bt][ks][j] += cf[j];
        }
      }
    }
  }

  // write z_q = sum of selected codebook rows
  #pragma unroll
  for(int bt=0;bt<2;bt++)
    #pragma unroll
    for(int ks=0;ks<2;ks++){
      float* zp = z_q + (row0 + bt*16 + l16)*64 + ks*32 + quad*8;
      float4 w0 = {qa[bt][ks][0], qa[bt][ks][1], qa[bt][ks][2], qa[bt][ks][3]};
      float4 w1 = {qa[bt][ks][4], qa[bt][ks][5], qa[bt][ks][6], qa[bt][ks][7]};
      *(float4*)zp = w0;
      *(float4*)(zp+4) = w1;
    }

  __syncthreads();
  if(tid < NQ_) atomicAdd(&loss[tid], sloss[tid]);
  for(int i=tid;i<NQ_*NEMB_;i+=256){
    int v = (&hist[0][0])[i];
    if(v) atomicAdd(&counts[i], v);
  }
}

// -------------------- ConvTranspose1d K=4 s=2 p=1 (64->256) + relu, MFMA
__global__ __launch_bounds__(256) void k_convT(
    const float* __restrict__ zq, const u16* __restrict__ wb4,
    const float* __restrict__ bias, u16* __restrict__ out){
  __shared__ __align__(16) u16 sxT[66][LP];
  __shared__ __align__(16) u16 sw4[4][128][LP];
  const int tid = threadIdx.x;
  const int bb  = blockIdx.z;
  const int co0 = blockIdx.y*128;
  const int t0  = blockIdx.x*64;
  const int wave = tid>>6, lane = tid&63;
  const int wm = wave & 1, wn = wave >> 1;
  const int quad = lane>>4, l16 = lane&15;

  f32x4 ae[4][2], ao[4][2];
  #pragma unroll
  for(int m=0;m<4;m++)
    #pragma unroll
    for(int n=0;n<2;n++){ ae[m][n]=(f32x4){0,0,0,0}; ao[m][n]=(f32x4){0,0,0,0}; }

  for(int cib=0; cib<NLAT; cib+=32){
    // stage x^T: rows t0-1..t0+64, 32 ci (fp32 -> bf16, transpose)
    for(int s=tid; s<66*32; s+=256){
      int ci = s/66, tt = s%66;
      int t = t0 - 1 + tt;
      float v = 0.f;
      if(t >= 0 && t < LENC) v = zq[((size_t)(bb*NLAT + cib + ci))*LENC + t];
      sxT[tt][ci] = f2b(v);
    }
    // stage weights: 4 taps x 128 co x 32 ci
    for(int s=tid; s<4*128*4; s+=256){
      int row = s>>2, ch = s&3;
      int tap = row>>7, cr = row&127;
      int4 v = *(const int4*)(wb4 + ((size_t)(tap*NHID + co0 + cr))*NLAT + cib + ch*8);
      *(int4*)&sw4[tap][cr][ch*8] = v;
    }
    __syncthreads();
    #pragma unroll
    for(int m=0;m<4;m++){
      int crow = wm*64 + m*16 + l16;
      bf16x8 a0 = *(const bf16x8*)&sw4[0][crow][quad*8];
      bf16x8 a1 = *(const bf16x8*)&sw4[1][crow][quad*8];
      bf16x8 a2 = *(const bf16x8*)&sw4[2][crow][quad*8];
      bf16x8 a3 = *(const bf16x8*)&sw4[3][crow][quad*8];
      #pragma unroll
      for(int n=0;n<2;n++){
        int off = wn*32 + n*16 + l16;
        bf16x8 bm = *(const bf16x8*)&sxT[off  ][quad*8];   // x[t-1]
        bf16x8 b0 = *(const bf16x8*)&sxT[off+1][quad*8];   // x[t]
        bf16x8 bp = *(const bf16x8*)&sxT[off+2][quad*8];   // x[t+1]
        ae[m][n] = __builtin_amdgcn_mfma_f32_16x16x32_bf16(a1, b0, ae[m][n], 0,0,0);
        ae[m][n] = __builtin_amdgcn_mfma_f32_16x16x32_bf16(a3, bm, ae[m][n], 0,0,0);
        ao[m][n] = __builtin_amdgcn_mfma_f32_16x16x32_bf16(a2, b0, ao[m][n], 0,0,0);
        ao[m][n] = __builtin_amdgcn_mfma_f32_16x16x32_bf16(a0, bp, ao[m][n], 0,0,0);
      }
    }
    __syncthreads();
  }

  #pragma unroll
  for(int m=0;m<4;m++){
    int co4 = co0 + wm*64 + m*16 + quad*4;
    float4 bv = *(const float4*)&bias[co4];
    #pragma unroll
    for(int n=0;n<2;n++){
      int t = t0 + wn*32 + n*16 + l16;
      int je = 2*t, jo = 2*t+1;
      ushort4 oe, oo;
      oe.x = f2b(fmaxf(ae[m][n][0]+bv.x, 0.f));
      oe.y = f2b(fmaxf(ae[m][n][1]+bv.y, 0.f));
      oe.z = f2b(fmaxf(ae[m][n][2]+bv.z, 0.f));
      oe.w = f2b(fmaxf(ae[m][n][3]+bv.w, 0.f));
      oo.x = f2b(fmaxf(ao[m][n][0]+bv.x, 0.f));
      oo.y = f2b(fmaxf(ao[m][n][1]+bv.y, 0.f));
      oo.z = f2b(fmaxf(ao[m][n][2]+bv.z, 0.f));
      oo.w = f2b(fmaxf(ao[m][n][3]+bv.w, 0.f));
      *(ushort4*)(out + ((size_t)(bb*LDEC + je))*NHID + co4) = oe;
      *(ushort4*)(out + ((size_t)(bb*LDEC + jo))*NHID + co4) = oo;
    }
  }
}

// -------------------- final ConvTranspose K=3 s=1 p=1 (256->1), f32 out
__global__ __launch_bounds__(256) void k_finalT(
    const u16* __restrict__ in, const float* __restrict__ w,
    const float* __restrict__ bias, float* __restrict__ out){
  __shared__ u16 sd[66][258];
  __shared__ float red[4][64];
  const int tid = threadIdx.x;
  const int j0 = blockIdx.x*64;
  const int bb = blockIdx.y;
  for(int s=tid; s<66*32; s+=256){
    int row = s>>5, ch = s&31;
    int l = j0 - 1 + row;
    int4 v = make_int4(0,0,0,0);
    if(l >= 0 && l < LDEC)
      v = *(const int4*)(in + ((size_t)(bb*LDEC + l))*NHID + ch*8);
    int* dst = (int*)&sd[row][ch*8];
    dst[0]=v.x; dst[1]=v.y; dst[2]=v.z; dst[3]=v.w;
  }
  __syncthreads();
  const int jl = tid & 63;
  const int part = tid >> 6;   // wave-uniform
  float acc = 0.f;
  for(int ci=0; ci<64; ci++){
    int cg = part*64 + ci;
    float w0 = w[cg*3+2], w1 = w[cg*3+1], w2 = w[cg*3+0];
    acc = fmaf(w0, b2f(sd[jl  ][cg]), acc);
    acc = fmaf(w1, b2f(sd[jl+1][cg]), acc);
    acc = fmaf(w2, b2f(sd[jl+2][cg]), acc);
  }
  red[part][jl] = acc;
  __syncthreads();
  if(tid < 64)
    out[(size_t)bb*NITEMS + j0 + tid] =
      bias[0] + red[0][tid] + red[1][tid] + red[2][tid] + red[3][tid];
}

// ------------------------------------ out projection (MFMA, split-bf16)
// part[kz][b][n] = sum_{k in chunk kz} dvec[b][k] * W[n][k]
// A = dvec rows (b), B = W cols (n).  4 cross-term MFMAs -> ~2^-18 rel error.
// block = 4 waves: wave (wb_,wn_): b-tiles wb_*4..+3 (64b), n = n0+wn_*32..+31.
// grid = (NITEMS/64 n-blocks, KC_ k-chunks); chunk = NITEMS/KC_ = 2048 k.
__global__ __launch_bounds__(256) void k_opmm(
    const u16* __restrict__ dvh, const u16* __restrict__ dvl,
    const float* __restrict__ Wm, float* __restrict__ part){
  const int tid = threadIdx.x;
  const int wave = tid>>6, lane = tid&63;
  const int quad = lane>>4, l16 = lane&15;
  const int wb_ = wave & 1;        // b-group (0: b 0-63, 1: b 64-127)
  const int wn_ = wave >> 1;       // n-group within block
  const int n0 = blockIdx.x*64;
  const int kz = blockIdx.y;
  const int n_wave = n0 + wn_*32;

  f32x4 acc[4][2];
  #pragma unroll
  for(int bt=0;bt<4;bt++)
    #pragma unroll
    for(int nt=0;nt<2;nt++) acc[bt][nt] = (f32x4){0.f,0.f,0.f,0.f};

  const size_t abase = (size_t)(wb_*64 + l16)*NITEMS + quad*8;
  const size_t wrow  = (size_t)(n_wave + l16)*NITEMS + quad*8;
  const int kbase = kz*(NITEMS/KC_);

  #pragma unroll 2
  for(int t=0; t<(NITEMS/KC_)/32; t++){
    const int k = kbase + t*32;
    bf16x8 ah[4], al[4];
    #pragma unroll
    for(int bt=0;bt<4;bt++){
      ah[bt] = *(const bf16x8*)(dvh + abase + (size_t)bt*16*NITEMS + k);
      al[bt] = *(const bf16x8*)(dvl + abase + (size_t)bt*16*NITEMS + k);
    }
    #pragma unroll
    for(int nt=0;nt<2;nt++){
      const float* wp = Wm + wrow + (size_t)nt*16*NITEMS + k;
      float4 wa = *(const float4*)wp;
      float4 wc = *(const float4*)(wp+4);
      float f[8] = {wa.x,wa.y,wa.z,wa.w,wc.x,wc.y,wc.z,wc.w};
      bf16x8 wh, wl;
      #pragma unroll
      for(int j=0;j<8;j++){
        u16 h = f2b(f[j]);
        wh[j] = (short)h;
        wl[j] = (short)f2b(f[j] - b2f(h));
      }
      #pragma unroll
      for(int bt=0;bt<4;bt++){
        acc[bt][nt] = __builtin_amdgcn_mfma_f32_16x16x32_bf16(ah[bt], wh, acc[bt][nt], 0,0,0);
        acc[bt][nt] = __builtin_amdgcn_mfma_f32_16x16x32_bf16(al[bt], wh, acc[bt][nt], 0,0,0);
        acc[bt][nt] = __builtin_amdgcn_mfma_f32_16x16x32_bf16(ah[bt], wl, acc[bt][nt], 0,0,0);
        acc[bt][nt] = __builtin_amdgcn_mfma_f32_16x16x32_bf16(al[bt], wl, acc[bt][nt], 0,0,0);
      }
    }
  }

  float* pp = part + (size_t)kz*NB*NITEMS;
  #pragma unroll
  for(int bt=0;bt<4;bt++){
    const int brow = wb_*64 + bt*16 + quad*4;
    #pragma unroll
    for(int nt=0;nt<2;nt++){
      const int n = n_wave + nt*16 + l16;
      #pragma unroll
      for(int i=0;i<4;i++)
        pp[(size_t)(brow+i)*NITEMS + n] = acc[bt][nt][i];
    }
  }
}

// out[b][n] = bias[n] + sum_kz part[kz][b][n]
__global__ __launch_bounds__(256) void k_opred(
    const float* __restrict__ part, const float* __restrict__ bias,
    float* __restrict__ out){
  const size_t i = ((size_t)blockIdx.x*256 + threadIdx.x)*4;
  float4 s = *(const float4*)&bias[(int)(i & (NITEMS-1))];
  #pragma unroll
  for(int kz=0;kz<KC_;kz++){
    float4 p = *(const float4*)&part[(size_t)kz*NB*NITEMS + i];
    s.x+=p.x; s.y+=p.y; s.z+=p.z; s.w+=p.w;
  }
  *(float4*)&out[i] = s;
}

// ------------------------------------------------- finalize scalars
__global__ void k_finalize(const float* __restrict__ loss, const int* __restrict__ counts,
                           float* __restrict__ out){
  __shared__ float sh[512];
  const int tid = threadIdx.x;
  float perp_sum = 0.f;
  for(int q=0;q<NQ_;q++){
    float avg = (float)counts[q*NEMB_+tid] / (float)NROWS;
    sh[tid] = avg*logf(avg + 1e-10f);
    __syncthreads();
    for(int s=256;s>0;s>>=1){ if(tid<s) sh[tid]+=sh[tid+s]; __syncthreads(); }
    if(tid==0) perp_sum += expf(-sh[0]);
    __syncthreads();
  }
  if(tid==0){
    float vl = 0.f;
    for(int q=0;q<NQ_;q++) vl += 1.25f*loss[q]/VQ_NELEM;
    out[0] = vl;
    out[1] = perp_sum/(float)NQ_;
  }
}

// =================================================================== launcher
extern "C" void kernel_launch(void* const* d_in, const int* in_sizes, int n_in,
                              void* d_out, int out_size, void* d_ws, size_t ws_size,
                              hipStream_t stream){
  (void)in_sizes; (void)n_in; (void)out_size;
  const int*   uid   = (const int*)d_in[0];
  const float* mat   = (const float*)d_in[1];
  const float* ec_w  = (const float*)d_in[2];
  const float* ec_b  = (const float*)d_in[3];
  const float* er_w1 = (const float*)d_in[4];
  const float* er_b1 = (const float*)d_in[5];
  const float* er_w2 = (const float*)d_in[6];
  const float* er_b2 = (const float*)d_in[7];
  const float* ef_w  = (const float*)d_in[8];
  const float* ef_b  = (const float*)d_in[9];
  const float* cb    = (const float*)d_in[10];
  const float* dt_w  = (const float*)d_in[11];
  const float* dt_b  = (const float*)d_in[12];
  const float* dr_w1 = (const float*)d_in[13];
  const float* dr_b1 = (const float*)d_in[14];
  const float* dr_w2 = (const float*)d_in[15];
  const float* dr_b2 = (const float*)d_in[16];
  const float* df_w  = (const float*)d_in[17];
  const float* df_b  = (const float*)d_in[18];
  const float* op_w  = (const float*)d_in[19];
  const float* op_b  = (const float*)d_in[20];
  float* outp = (float*)d_out;

  // ---------------- workspace: fixed region, then chunk buffers
  float* W = (float*)d_ws;
  size_t o = 0;
  float* xg    = W + o; o += (size_t)NB*NITEMS;
  float* dvec  = W + o; o += (size_t)NB*NITEMS;
  u16* wb3e0 = (u16*)(W + o); o += 3*NHID*NHID/2;
  u16* wb3e1 = (u16*)(W + o); o += 3*NHID*NHID/2;
  u16* wb3d0 = (u16*)(W + o); o += 3*NHID*NHID/2;
  u16* wb3d1 = (u16*)(W + o); o += 3*NHID*NHID/2;
  u16* wbF   = (u16*)(W + o); o += 3*NLAT*NHID/2;
  u16* wb1e0 = (u16*)(W + o); o += NHID*NHID/2;
  u16* wb1e1 = (u16*)(W + o); o += NHID*NHID/2;
  u16* wb1d0 = (u16*)(W + o); o += NHID*NHID/2;
  u16* wb1d1 = (u16*)(W + o); o += NHID*NHID/2;
  u16* wbT   = (u16*)(W + o); o += 4*NLAT*NHID/2;
  u16* cbh   = (u16*)(W + o); o += (size_t)NQ_*NEMB_*64/2;
  u16* cbl   = (u16*)(W + o); o += (size_t)NQ_*NEMB_*64/2;
  float* cb2   = W + o; o += NQ_*NEMB_;
  float* lossb = W + o; o += 4;
  int*   counts= (int*)(W + o); o += NQ_*NEMB_;
  u16* dvh   = (u16*)(W + o); o += (size_t)NB*NITEMS/2;
  u16* dvl   = (u16*)(W + o); o += (size_t)NB*NITEMS/2;
  float* partb = W + o; o += (size_t)KC_*NB*NITEMS;
  const size_t fixedF = o;

  // chunk buffers: two bf16 act buffers of CB*LDEC*NHID u16 each
  const size_t perBF = (size_t)LDEC*NHID/2;     // floats per batch elem per buffer
  size_t availF = ws_size/sizeof(float) > fixedF ? ws_size/sizeof(float) - fixedF : 0;
  int CB = 128;
  while(CB > 1 && (size_t)CB*2*perBF > availF) CB >>= 1;

  k_zero<<<(4 + NQ_*NEMB_ + 255)/256,256,0,stream>>>(lossb, 4 + NQ_*NEMB_);

  // weight packs (fp32 -> bf16, tap-major [k][co][ci])
  k_packw<<<(3*NHID*NHID+255)/256,256,0,stream>>>(er_w1,             wb3e0, NHID, NHID, 3);
  k_packw<<<(3*NHID*NHID+255)/256,256,0,stream>>>(er_w1+3*NHID*NHID, wb3e1, NHID, NHID, 3);
  k_packw<<<(3*NHID*NHID+255)/256,256,0,stream>>>(dr_w1,             wb3d0, NHID, NHID, 3);
  k_packw<<<(3*NHID*NHID+255)/256,256,0,stream>>>(dr_w1+3*NHID*NHID, wb3d1, NHID, NHID, 3);
  k_packw<<<(3*NLAT*NHID+255)/256,256,0,stream>>>(ef_w,              wbF,   NLAT, NHID, 3);
  k_packw<<<(NHID*NHID+255)/256,256,0,stream>>>(er_w2,               wb1e0, NHID, NHID, 1);
  k_packw<<<(NHID*NHID+255)/256,256,0,stream>>>(er_w2+NHID*NHID,     wb1e1, NHID, NHID, 1);
  k_packw<<<(NHID*NHID+255)/256,256,0,stream>>>(dr_w2,               wb1d0, NHID, NHID, 1);
  k_packw<<<(NHID*NHID+255)/256,256,0,stream>>>(dr_w2+NHID*NHID,     wb1d1, NHID, NHID, 1);
  k_packwT<<<(4*NLAT*NHID+255)/256,256,0,stream>>>(dt_w, wbT);
  k_cbsplit<<<(NQ_*NEMB_*64)/256,256,0,stream>>>(cb, cbh, cbl);
  k_cbnorm<<<(NQ_*NEMB_+255)/256,256,0,stream>>>(cb, cb2);

  k_gather<<<dim3(NITEMS/256, NB),256,0,stream>>>(uid, mat, xg);

  u16* D0b = (u16*)(W + fixedF);
  u16* D1b = D0b + (size_t)CB*LDEC*NHID;

  for(int c0 = 0; c0 < NB; c0 += CB){
    u16* E0 = D0b;                                  // [CB][4096][256] bf16
    u16* E1 = D0b + (size_t)CB*LENC*NHID;
    float* z_e = (float*)D1b;                       // [CB][64][4096] f32
    float* z_q = z_e + (size_t)CB*NLAT*LENC;
    const float* xgc = xg + (size_t)c0*NITEMS;
    float* dvc = dvec + (size_t)c0*NITEMS;

    // ---- encoder
    k_enc0<<<dim3(LENC/16, CB),256,0,stream>>>(xgc, ec_w, ec_b, E0);
    k_cgemm<256,256,3,2,2,1,0,0><<<dim3(LENC/128, 2, CB),256,0,stream>>>(E0, wb3e0, er_b1,      nullptr, E1, LENC);
    k_cgemm<256,256,1,2,2,1,1,0><<<dim3(LENC/128, 2, CB),256,0,stream>>>(E1, wb1e0, er_b2,      E0,      E0, LENC);
    k_cgemm<256,256,3,2,2,1,0,0><<<dim3(LENC/128, 2, CB),256,0,stream>>>(E0, wb3e1, er_b1+NHID, nullptr, E1, LENC);
    k_cgemm<256,256,1,2,2,1,1,0><<<dim3(LENC/128, 2, CB),256,0,stream>>>(E1, wb1e1, er_b2+NHID, E0,      E0, LENC);
    k_cgemm<256, 64,3,1,4,0,0,1><<<dim3(LENC/256, 1, CB),256,0,stream>>>(E0, wbF,   ef_b,       nullptr, z_e, LENC);

    // ---- residual VQ (MFMA split-bf16): 128 rows/block, 32 rows/wave
    k_vq<<<CB*32,256,0,stream>>>(z_e, cb, cbh, cbl, cb2, z_q, lossb, counts);

    // ---- decoder
    k_convT<<<dim3(LENC/64, 2, CB),256,0,stream>>>(z_q, wbT, dt_b, D0b);
    k_cgemm<256,256,3,2,2,1,0,0><<<dim3(LDEC/128, 2, CB),256,0,stream>>>(D0b, wb3d0, dr_b1,      nullptr, D1b, LDEC);
    k_cgemm<256,256,1,2,2,1,1,0><<<dim3(LDEC/128, 2, CB),256,0,stream>>>(D1b, wb1d0, dr_b2,      D0b,     D0b, LDEC);
    k_cgemm<256,256,3,2,2,1,0,0><<<dim3(LDEC/128, 2, CB),256,0,stream>>>(D0b, wb3d1, dr_b1+NHID, nullptr, D1b, LDEC);
    k_cgemm<256,256,1,2,2,1,1,0><<<dim3(LDEC/128, 2, CB),256,0,stream>>>(D1b, wb1d1, dr_b2+NHID, D0b,     D0b, LDEC);
    k_finalT<<<dim3(LDEC/64, CB),256,0,stream>>>(D0b, df_w, df_b, dvc);
  }

  // ---- head: recon = dvec @ W^T + b  (MFMA split-bf16, K-chunked partials)
  k_packdv<<<NB*NITEMS/256,256,0,stream>>>(dvec, dvh, dvl);
  k_opmm<<<dim3(NITEMS/64, KC_),256,0,stream>>>(dvh, dvl, op_w, partb);
  k_opred<<<NB*NITEMS/1024,256,0,stream>>>(partb, op_b, outp);
  k_finalize<<<1,512,0,stream>>>(lossb, counts, outp + (size_t)NB*NITEMS);
}

// Round 3
// 6477.065 us; speedup vs baseline: 1.6609x; 1.0589x over previous
//
#include <hip/hip_runtime.h>
#include <math.h>

#define NB 128
#define NITEMS 8192
#define NHID 256
#define NLAT 64
#define NEMB_ 512
#define NQ_ 4
#define LENC 4096
#define LDEC 8192
#define NROWS 524288            // NB*NLAT*LENC/64
#define VQ_NELEM 33554432.0f    // NB*NLAT*LENC
#define KC_ 4                   // out-proj K-chunks

typedef unsigned short u16;
typedef __attribute__((ext_vector_type(8))) short bf16x8;
typedef __attribute__((ext_vector_type(4))) float f32x4;

__device__ __forceinline__ u16 f2b(float f){
  unsigned u = __float_as_uint(f);
  unsigned r = (u + 0x7FFFu + ((u>>16)&1u)) >> 16;
  return (u16)r;
}
__device__ __forceinline__ float b2f(u16 h){
  return __uint_as_float(((unsigned)h)<<16);
}

// ---------------------------------------------------------------- small prep
__global__ void k_zero(float* __restrict__ p, int n){
  int i = blockIdx.x*256 + threadIdx.x;
  if(i < n) p[i] = 0.f;
}

__global__ void k_gather(const int* __restrict__ uid, const float* __restrict__ mat,
                         float* __restrict__ x){
  int b = blockIdx.y;
  int i = blockIdx.x*256 + threadIdx.x;
  x[(size_t)b*NITEMS + i] = mat[(size_t)uid[b]*NITEMS + i];
}

// w[CO][CI][K] f32 -> wb[k][co][ci] bf16
__global__ void k_packw(const float* __restrict__ w, u16* __restrict__ wb,
                        int CO, int CI, int K){
  int idx = blockIdx.x*256 + threadIdx.x;
  int n = CO*CI*K;
  if(idx >= n) return;
  int k  = idx % K;
  int ci = (idx / K) % CI;
  int co = idx / (K*CI);
  wb[((size_t)k*CO + co)*CI + ci] = f2b(w[idx]);
}

// ConvTranspose w[CI=64][CO=256][4] f32 -> wb[tap][co][ci] bf16
__global__ void k_packwT(const float* __restrict__ w, u16* __restrict__ wb){
  int idx = blockIdx.x*256 + threadIdx.x;
  if(idx >= 64*256*4) return;
  int k  = idx % 4;
  int co = (idx / 4) % 256;
  int ci = idx / (4*256);
  wb[((size_t)k*256 + co)*64 + ci] = f2b(w[idx]);
}

// split-precision codebook for MFMA distance GEMM:
// s = -2*cb ; cbh = bf16_rne(s) ; cbl = bf16_rne(s - cbh)
__global__ void k_cbsplit(const float* __restrict__ cb, u16* __restrict__ h,
                          u16* __restrict__ l){
  int idx = blockIdx.x*256 + threadIdx.x;   // NQ*NEMB*64 total
  float v = -2.0f*cb[idx];
  u16 hh = f2b(v);
  h[idx] = hh;
  l[idx] = f2b(v - b2f(hh));
}

__global__ void k_cbnorm(const float* __restrict__ cb, float* __restrict__ cb2){
  int idx = blockIdx.x*256 + threadIdx.x;
  if(idx >= NQ_*NEMB_) return;
  const float* p = cb + (size_t)idx*64;
  float s = 0.f;
  #pragma unroll
  for(int d=0; d<64; d++) s = fmaf(p[d], p[d], s);
  cb2[idx] = s;
}

// dvec f32 [B][NITEMS] -> hi/lo bf16 (for out-proj MFMA)
__global__ void k_packdv(const float* __restrict__ d, u16* __restrict__ h,
                         u16* __restrict__ l){
  int i = blockIdx.x*256 + threadIdx.x;
  float v = d[i];
  u16 hh = f2b(v);
  h[i] = hh;
  l[i] = f2b(v - b2f(hh));
}

// --------------------------- encoder first conv (C_in=1, K=4, s=2), bf16 ch-last
__global__ __launch_bounds__(256) void k_enc0(
    const float* __restrict__ x, const float* __restrict__ w,
    const float* __restrict__ bias, u16* __restrict__ out){
  const int co = threadIdx.x;
  const int b  = blockIdx.y;
  const int l0 = blockIdx.x*16;
  const float* xr = x + (size_t)b*NITEMS;
  float4 wv = *(const float4*)&w[co*4];
  float bv = bias[co];
  for(int dl=0; dl<16; dl++){
    int l = l0 + dl;
    int i0 = 2*l - 1;
    float x0 = (i0 >= 0) ? xr[i0] : 0.f;
    float x1 = xr[i0+1];
    float x2 = xr[i0+2];
    float x3 = (i0+3 < NITEMS) ? xr[i0+3] : 0.f;
    float acc = bv;
    acc = fmaf(wv.x, x0, acc); acc = fmaf(wv.y, x1, acc);
    acc = fmaf(wv.z, x2, acc); acc = fmaf(wv.w, x3, acc);
    out[((size_t)(b*LENC + l))*NHID + co] = f2b(fmaxf(acc, 0.f));
  }
}

// --------------------------------------------- generic implicit-GEMM conv (MFMA)
#define LP 40   // LDS row stride in bf16 (80B: 16B-aligned, odd bank groups)
template<int CIN, int COUT, int KK, int WM, int WN, int RELU, int RES, int CHF>
__global__ __launch_bounds__(256) void k_cgemm(
    const u16* __restrict__ in, const u16* __restrict__ wb,
    const float* __restrict__ bias, const u16* __restrict__ res,
    void* __restrict__ outv, int L){
  constexpr int CO_T = WM*64;
  constexpr int LT   = WN*64;
  constexpr int PAD  = (KK-1)/2;
  constexpr int RXS  = LT + KK - 1;
  __shared__ __align__(16) u16 sx[RXS][LP];
  __shared__ __align__(16) u16 sw[KK][CO_T][LP];

  const int tid = threadIdx.x;
  const int bb  = blockIdx.z;
  const int co0 = blockIdx.y*CO_T;
  const int l0  = blockIdx.x*LT;
  const int wave = tid>>6, lane = tid&63;
  const int wm = wave % WM, wn = wave / WM;
  const int quad = lane>>4, l16 = lane&15;

  f32x4 acc[4][4];
  #pragma unroll
  for(int m=0;m<4;m++)
    #pragma unroll
    for(int n=0;n<4;n++) acc[m][n] = (f32x4){0.f,0.f,0.f,0.f};

  for(int cib=0; cib<CIN; cib+=32){
    for(int s=tid; s<RXS*4; s+=256){
      int row = s>>2, ch = s&3;
      int l = l0 - PAD + row;
      int4 v;
      if(l >= 0 && l < L)
        v = *(const int4*)(in + ((size_t)(bb*L + l))*CIN + cib + ch*8);
      else
        v = make_int4(0,0,0,0);
      *(int4*)&sx[row][ch*8] = v;
    }
    for(int s=tid; s<KK*CO_T*4; s+=256){
      int row = s>>2, ch = s&3;
      int kk = row / CO_T, cr = row % CO_T;
      int4 v = *(const int4*)(wb + ((size_t)(kk*COUT + co0 + cr))*CIN + cib + ch*8);
      *(int4*)&sw[kk][cr][ch*8] = v;
    }
    __syncthreads();
    #pragma unroll
    for(int kk=0; kk<KK; kk++){
      bf16x8 af[4];
      #pragma unroll
      for(int m=0;m<4;m++)
        af[m] = *(const bf16x8*)&sw[kk][wm*64 + m*16 + l16][quad*8];
      #pragma unroll
      for(int n=0;n<4;n++){
        bf16x8 bf = *(const bf16x8*)&sx[wn*64 + n*16 + l16 + kk][quad*8];
        #pragma unroll
        for(int m=0;m<4;m++)
          acc[m][n] = __builtin_amdgcn_mfma_f32_16x16x32_bf16(af[m], bf, acc[m][n], 0,0,0);
      }
    }
    __syncthreads();
  }

  #pragma unroll
  for(int m=0;m<4;m++){
    int co4 = co0 + wm*64 + m*16 + quad*4;
    float4 bv = *(const float4*)&bias[co4];
    #pragma unroll
    for(int n=0;n<4;n++){
      int l = l0 + wn*64 + n*16 + l16;
      float v0 = acc[m][n][0] + bv.x;
      float v1 = acc[m][n][1] + bv.y;
      float v2 = acc[m][n][2] + bv.z;
      float v3 = acc[m][n][3] + bv.w;
      if(RES){
        ushort4 rv = *(const ushort4*)(res + ((size_t)(bb*L + l))*COUT + co4);
        v0 += b2f(rv.x); v1 += b2f(rv.y); v2 += b2f(rv.z); v3 += b2f(rv.w);
      }
      if(RELU){
        v0 = fmaxf(v0,0.f); v1 = fmaxf(v1,0.f); v2 = fmaxf(v2,0.f); v3 = fmaxf(v3,0.f);
      }
      if(CHF){
        float* of = (float*)outv;
        of[((size_t)(bb*COUT + co4+0))*L + l] = v0;
        of[((size_t)(bb*COUT + co4+1))*L + l] = v1;
        of[((size_t)(bb*COUT + co4+2))*L + l] = v2;
        of[((size_t)(bb*COUT + co4+3))*L + l] = v3;
      }else{
        u16* ob = (u16*)outv;
        ushort4 o;
        o.x = f2b(v0); o.y = f2b(v1); o.z = f2b(v2); o.w = f2b(v3);
        *(ushort4*)(ob + ((size_t)(bb*L + l))*COUT + co4) = o;
      }
    }
  }
}

// --------------------------------------------------- residual-VQ (all 4 stages)
// MFMA distance GEMM, split-bf16 (dot(r,-2c) = Ah.Bh + Ah.Bl + Al.Bh).
// One wave owns 64 rows (4 B-tiles of 16); 24 MFMAs per 16-code tile.
// A-frags (codes) prefetched 2-3 tiles ahead via a 3-slot rotation (static idx).
// z_q = z_e - r_final (no per-stage accumulator; exact to ~2^-17).
#define VQ_LOADT(S, T) { \
  const u16* nh_ = Ah + (size_t)(T)*1024; \
  const u16* nl_ = Al + (size_t)(T)*1024; \
  s_h0[S] = *(const bf16x8*)(nh_); \
  s_h1[S] = *(const bf16x8*)(nh_ + 32); \
  s_l0[S] = *(const bf16x8*)(nl_); \
  s_l1[S] = *(const bf16x8*)(nl_ + 32); \
}

#define VQ_DOT(S, T) { \
  f32x4 ac0=(f32x4){0.f,0.f,0.f,0.f}, ac1=ac0, ac2=ac0, ac3=ac0; \
  ac0 = __builtin_amdgcn_mfma_f32_16x16x32_bf16(s_h0[S], vbh[0][0], ac0,0,0,0); \
  ac1 = __builtin_amdgcn_mfma_f32_16x16x32_bf16(s_h0[S], vbh[1][0], ac1,0,0,0); \
  ac2 = __builtin_amdgcn_mfma_f32_16x16x32_bf16(s_h0[S], vbh[2][0], ac2,0,0,0); \
  ac3 = __builtin_amdgcn_mfma_f32_16x16x32_bf16(s_h0[S], vbh[3][0], ac3,0,0,0); \
  ac0 = __builtin_amdgcn_mfma_f32_16x16x32_bf16(s_h0[S], vbl[0][0], ac0,0,0,0); \
  ac1 = __builtin_amdgcn_mfma_f32_16x16x32_bf16(s_h0[S], vbl[1][0], ac1,0,0,0); \
  ac2 = __builtin_amdgcn_mfma_f32_16x16x32_bf16(s_h0[S], vbl[2][0], ac2,0,0,0); \
  ac3 = __builtin_amdgcn_mfma_f32_16x16x32_bf16(s_h0[S], vbl[3][0], ac3,0,0,0); \
  ac0 = __builtin_amdgcn_mfma_f32_16x16x32_bf16(s_l0[S], vbh[0][0], ac0,0,0,0); \
  ac1 = __builtin_amdgcn_mfma_f32_16x16x32_bf16(s_l0[S], vbh[1][0], ac1,0,0,0); \
  ac2 = __builtin_amdgcn_mfma_f32_16x16x32_bf16(s_l0[S], vbh[2][0], ac2,0,0,0); \
  ac3 = __builtin_amdgcn_mfma_f32_16x16x32_bf16(s_l0[S], vbh[3][0], ac3,0,0,0); \
  ac0 = __builtin_amdgcn_mfma_f32_16x16x32_bf16(s_h1[S], vbh[0][1], ac0,0,0,0); \
  ac1 = __builtin_amdgcn_mfma_f32_16x16x32_bf16(s_h1[S], vbh[1][1], ac1,0,0,0); \
  ac2 = __builtin_amdgcn_mfma_f32_16x16x32_bf16(s_h1[S], vbh[2][1], ac2,0,0,0); \
  ac3 = __builtin_amdgcn_mfma_f32_16x16x32_bf16(s_h1[S], vbh[3][1], ac3,0,0,0); \
  ac0 = __builtin_amdgcn_mfma_f32_16x16x32_bf16(s_h1[S], vbl[0][1], ac0,0,0,0); \
  ac1 = __builtin_amdgcn_mfma_f32_16x16x32_bf16(s_h1[S], vbl[1][1], ac1,0,0,0); \
  ac2 = __builtin_amdgcn_mfma_f32_16x16x32_bf16(s_h1[S], vbl[2][1], ac2,0,0,0); \
  ac3 = __builtin_amdgcn_mfma_f32_16x16x32_bf16(s_h1[S], vbl[3][1], ac3,0,0,0); \
  ac0 = __builtin_amdgcn_mfma_f32_16x16x32_bf16(s_l1[S], vbh[0][1], ac0,0,0,0); \
  ac1 = __builtin_amdgcn_mfma_f32_16x16x32_bf16(s_l1[S], vbh[1][1], ac1,0,0,0); \
  ac2 = __builtin_amdgcn_mfma_f32_16x16x32_bf16(s_l1[S], vbh[2][1], ac2,0,0,0); \
  ac3 = __builtin_amdgcn_mfma_f32_16x16x32_bf16(s_l1[S], vbh[3][1], ac3,0,0,0); \
  float4 c2v = *(const float4*)(c2q + (T)*16 + quad*4); \
  const float* c2a = (const float*)&c2v; \
  _Pragma("unroll") \
  for(int i_=0;i_<4;i_++){ \
    int code = (T)*16 + quad*4 + i_; \
    float d0 = ac0[i_] + c2a[i_]; \
    float d1 = ac1[i_] + c2a[i_]; \
    float d2 = ac2[i_] + c2a[i_]; \
    float d3 = ac3[i_] + c2a[i_]; \
    if(d0 < best[0]){ best[0]=d0; bi[0]=code; } \
    if(d1 < best[1]){ best[1]=d1; bi[1]=code; } \
    if(d2 < best[2]){ best[2]=d2; bi[2]=code; } \
    if(d3 < best[3]){ best[3]=d3; bi[3]=code; } \
  } \
}

__global__ __launch_bounds__(256) void k_vq(
    const float* __restrict__ z_e, const float* __restrict__ cb,
    const u16* __restrict__ cbh, const u16* __restrict__ cbl,
    const float* __restrict__ cb2,
    float* __restrict__ z_q, float* __restrict__ loss, int* __restrict__ counts){
  __shared__ int hist[NQ_][NEMB_];
  __shared__ float sloss[NQ_];
  const int tid = threadIdx.x;
  for(int i=tid;i<NQ_*NEMB_;i+=256) (&hist[0][0])[i]=0;
  if(tid < NQ_) sloss[tid] = 0.f;
  __syncthreads();

  const int lane = tid & 63, wave = tid >> 6;
  const int quad = lane >> 4, l16 = lane & 15;
  const size_t row0 = (size_t)blockIdx.x*256 + (size_t)wave*64;

  // residual hi/lo B-frags [bt][kstep]
  bf16x8 vbh[4][2], vbl[4][2];
  #pragma unroll
  for(int bt=0;bt<4;bt++){
    #pragma unroll
    for(int ks=0;ks<2;ks++){
      const float* zp = z_e + (row0 + bt*16 + l16)*64 + ks*32 + quad*8;
      float4 v0 = *(const float4*)zp;
      float4 v1 = *(const float4*)(zp+4);
      float f[8] = {v0.x,v0.y,v0.z,v0.w,v1.x,v1.y,v1.z,v1.w};
      #pragma unroll
      for(int j=0;j<8;j++){
        u16 h = f2b(f[j]);
        vbh[bt][ks][j] = (short)h;
        vbl[bt][ks][j] = (short)f2b(f[j] - b2f(h));
      }
    }
  }

  #pragma unroll 1
  for(int q=0;q<NQ_;q++){
    const u16* Ah = cbh + (size_t)q*NEMB_*64 + (size_t)l16*64 + quad*8;
    const u16* Al = cbl + (size_t)q*NEMB_*64 + (size_t)l16*64 + quad*8;
    const float* c2q = cb2 + q*NEMB_;

    // |r|^2 partial over this lane's 16 dims per row (reduced across quads below)
    float rq[4];
    #pragma unroll
    for(int bt=0;bt<4;bt++){
      float s = 0.f;
      #pragma unroll
      for(int ks=0;ks<2;ks++)
        #pragma unroll
        for(int j=0;j<8;j++){
          float r = b2f((u16)vbh[bt][ks][j]) + b2f((u16)vbl[bt][ks][j]);
          s = fmaf(r,r,s);
        }
      rq[bt] = s;
    }

    float best[4] = {3.0e38f,3.0e38f,3.0e38f,3.0e38f};
    int   bi[4]   = {0,0,0,0};

    // 3-slot rotating prefetch: loads issue ~2 tile-iterations before use
    bf16x8 s_h0[3], s_h1[3], s_l0[3], s_l1[3];
    VQ_LOADT(0, 0);
    VQ_LOADT(1, 1);
    #pragma unroll 1
    for(int t=0; t<30; t+=3){
      VQ_LOADT(2, t+2);  VQ_DOT(0, t);
      VQ_LOADT(0, t+3);  VQ_DOT(1, t+1);
      VQ_LOADT(1, t+4);  VQ_DOT(2, t+2);
    }
    VQ_DOT(0, 30);
    VQ_DOT(1, 31);

    // cross-quad reduce: argmin (index tie-break) + |r|^2 sum
    #pragma unroll
    for(int bt=0;bt<4;bt++){
      #pragma unroll
      for(int off=16; off<=32; off<<=1){
        float ob = __shfl_xor(best[bt], off); int oi = __shfl_xor(bi[bt], off);
        if(ob < best[bt] || (ob == best[bt] && oi < bi[bt])){ best[bt]=ob; bi[bt]=oi; }
        rq[bt] += __shfl_xor(rq[bt], off);
      }
    }

    // loss: sum over rows of |r|^2 + (|c|^2 - 2 r.c)_best
    float v = (rq[0]+best[0]) + (rq[1]+best[1]) + (rq[2]+best[2]) + (rq[3]+best[3]);
    #pragma unroll
    for(int off=1; off<=8; off<<=1) v += __shfl_xor(v, off);
    if(lane == 0) atomicAdd(&sloss[q], v);
    if(quad == 0){
      atomicAdd(&hist[q][bi[0]], 1);
      atomicAdd(&hist[q][bi[1]], 1);
      atomicAdd(&hist[q][bi[2]], 1);
      atomicAdd(&hist[q][bi[3]], 1);
    }

    // residual -= chosen code; re-split hi/lo
    #pragma unroll
    for(int bt=0;bt<4;bt++){
      const float* cp = cb + ((size_t)q*NEMB_ + bi[bt])*64 + quad*8;
      #pragma unroll
      for(int ks=0;ks<2;ks++){
        float4 c0 = *(const float4*)(cp + ks*32);
        float4 c1 = *(const float4*)(cp + ks*32 + 4);
        float cf[8] = {c0.x,c0.y,c0.z,c0.w,c1.x,c1.y,c1.z,c1.w};
        #pragma unroll
        for(int j=0;j<8;j++){
          float r = b2f((u16)vbh[bt][ks][j]) + b2f((u16)vbl[bt][ks][j]) - cf[j];
          u16 h = f2b(r);
          vbh[bt][ks][j] = (short)h;
          vbl[bt][ks][j] = (short)f2b(r - b2f(h));
        }
      }
    }
  }

  // z_q = z_e - r_final
  #pragma unroll
  for(int bt=0;bt<4;bt++){
    #pragma unroll
    for(int ks=0;ks<2;ks++){
      const float* zp = z_e + (row0 + bt*16 + l16)*64 + ks*32 + quad*8;
      float*       qp = z_q + (row0 + bt*16 + l16)*64 + ks*32 + quad*8;
      float4 z0 = *(const float4*)zp;
      float4 z1 = *(const float4*)(zp+4);
      float zf[8] = {z0.x,z0.y,z0.z,z0.w,z1.x,z1.y,z1.z,z1.w};
      float o[8];
      #pragma unroll
      for(int j=0;j<8;j++)
        o[j] = zf[j] - (b2f((u16)vbh[bt][ks][j]) + b2f((u16)vbl[bt][ks][j]));
      float4 w0 = {o[0],o[1],o[2],o[3]};
      float4 w1 = {o[4],o[5],o[6],o[7]};
      *(float4*)qp = w0;
      *(float4*)(qp+4) = w1;
    }
  }

  __syncthreads();
  if(tid < NQ_) atomicAdd(&loss[tid], sloss[tid]);
  for(int i=tid;i<NQ_*NEMB_;i+=256){
    int v = (&hist[0][0])[i];
    if(v) atomicAdd(&counts[i], v);
  }
}

// -------------------- ConvTranspose1d K=4 s=2 p=1 (64->256) + relu, MFMA
__global__ __launch_bounds__(256) void k_convT(
    const float* __restrict__ zq, const u16* __restrict__ wb4,
    const float* __restrict__ bias, u16* __restrict__ out){
  __shared__ __align__(16) u16 sxT[66][LP];
  __shared__ __align__(16) u16 sw4[4][128][LP];
  const int tid = threadIdx.x;
  const int bb  = blockIdx.z;
  const int co0 = blockIdx.y*128;
  const int t0  = blockIdx.x*64;
  const int wave = tid>>6, lane = tid&63;
  const int wm = wave & 1, wn = wave >> 1;
  const int quad = lane>>4, l16 = lane&15;

  f32x4 ae[4][2], ao[4][2];
  #pragma unroll
  for(int m=0;m<4;m++)
    #pragma unroll
    for(int n=0;n<2;n++){ ae[m][n]=(f32x4){0,0,0,0}; ao[m][n]=(f32x4){0,0,0,0}; }

  for(int cib=0; cib<NLAT; cib+=32){
    for(int s=tid; s<66*32; s+=256){
      int ci = s/66, tt = s%66;
      int t = t0 - 1 + tt;
      float v = 0.f;
      if(t >= 0 && t < LENC) v = zq[((size_t)(bb*NLAT + cib + ci))*LENC + t];
      sxT[tt][ci] = f2b(v);
    }
    for(int s=tid; s<4*128*4; s+=256){
      int row = s>>2, ch = s&3;
      int tap = row>>7, cr = row&127;
      int4 v = *(const int4*)(wb4 + ((size_t)(tap*NHID + co0 + cr))*NLAT + cib + ch*8);
      *(int4*)&sw4[tap][cr][ch*8] = v;
    }
    __syncthreads();
    #pragma unroll
    for(int m=0;m<4;m++){
      int crow = wm*64 + m*16 + l16;
      bf16x8 a0 = *(const bf16x8*)&sw4[0][crow][quad*8];
      bf16x8 a1 = *(const bf16x8*)&sw4[1][crow][quad*8];
      bf16x8 a2 = *(const bf16x8*)&sw4[2][crow][quad*8];
      bf16x8 a3 = *(const bf16x8*)&sw4[3][crow][quad*8];
      #pragma unroll
      for(int n=0;n<2;n++){
        int off = wn*32 + n*16 + l16;
        bf16x8 bm = *(const bf16x8*)&sxT[off  ][quad*8];   // x[t-1]
        bf16x8 b0 = *(const bf16x8*)&sxT[off+1][quad*8];   // x[t]
        bf16x8 bp = *(const bf16x8*)&sxT[off+2][quad*8];   // x[t+1]
        ae[m][n] = __builtin_amdgcn_mfma_f32_16x16x32_bf16(a1, b0, ae[m][n], 0,0,0);
        ae[m][n] = __builtin_amdgcn_mfma_f32_16x16x32_bf16(a3, bm, ae[m][n], 0,0,0);
        ao[m][n] = __builtin_amdgcn_mfma_f32_16x16x32_bf16(a2, b0, ao[m][n], 0,0,0);
        ao[m][n] = __builtin_amdgcn_mfma_f32_16x16x32_bf16(a0, bp, ao[m][n], 0,0,0);
      }
    }
    __syncthreads();
  }

  #pragma unroll
  for(int m=0;m<4;m++){
    int co4 = co0 + wm*64 + m*16 + quad*4;
    float4 bv = *(const float4*)&bias[co4];
    #pragma unroll
    for(int n=0;n<2;n++){
      int t = t0 + wn*32 + n*16 + l16;
      int je = 2*t, jo = 2*t+1;
      ushort4 oe, oo;
      oe.x = f2b(fmaxf(ae[m][n][0]+bv.x, 0.f));
      oe.y = f2b(fmaxf(ae[m][n][1]+bv.y, 0.f));
      oe.z = f2b(fmaxf(ae[m][n][2]+bv.z, 0.f));
      oe.w = f2b(fmaxf(ae[m][n][3]+bv.w, 0.f));
      oo.x = f2b(fmaxf(ao[m][n][0]+bv.x, 0.f));
      oo.y = f2b(fmaxf(ao[m][n][1]+bv.y, 0.f));
      oo.z = f2b(fmaxf(ao[m][n][2]+bv.z, 0.f));
      oo.w = f2b(fmaxf(ao[m][n][3]+bv.w, 0.f));
      *(ushort4*)(out + ((size_t)(bb*LDEC + je))*NHID + co4) = oe;
      *(ushort4*)(out + ((size_t)(bb*LDEC + jo))*NHID + co4) = oo;
    }
  }
}

// -------------------- final ConvTranspose K=3 s=1 p=1 (256->1), f32 out
__global__ __launch_bounds__(256) void k_finalT(
    const u16* __restrict__ in, const float* __restrict__ w,
    const float* __restrict__ bias, float* __restrict__ out){
  __shared__ u16 sd[66][258];
  __shared__ float red[4][64];
  const int tid = threadIdx.x;
  const int j0 = blockIdx.x*64;
  const int bb = blockIdx.y;
  for(int s=tid; s<66*32; s+=256){
    int row = s>>5, ch = s&31;
    int l = j0 - 1 + row;
    int4 v = make_int4(0,0,0,0);
    if(l >= 0 && l < LDEC)
      v = *(const int4*)(in + ((size_t)(bb*LDEC + l))*NHID + ch*8);
    int* dst = (int*)&sd[row][ch*8];
    dst[0]=v.x; dst[1]=v.y; dst[2]=v.z; dst[3]=v.w;
  }
  __syncthreads();
  const int jl = tid & 63;
  const int part = tid >> 6;   // wave-uniform
  float acc = 0.f;
  for(int ci=0; ci<64; ci++){
    int cg = part*64 + ci;
    float w0 = w[cg*3+2], w1 = w[cg*3+1], w2 = w[cg*3+0];
    acc = fmaf(w0, b2f(sd[jl  ][cg]), acc);
    acc = fmaf(w1, b2f(sd[jl+1][cg]), acc);
    acc = fmaf(w2, b2f(sd[jl+2][cg]), acc);
  }
  red[part][jl] = acc;
  __syncthreads();
  if(tid < 64)
    out[(size_t)bb*NITEMS + j0 + tid] =
      bias[0] + red[0][tid] + red[1][tid] + red[2][tid] + red[3][tid];
}

// ------------------------------------ out projection (MFMA, split-bf16)
__global__ __launch_bounds__(256) void k_opmm(
    const u16* __restrict__ dvh, const u16* __restrict__ dvl,
    const float* __restrict__ Wm, float* __restrict__ part){
  const int tid = threadIdx.x;
  const int wave = tid>>6, lane = tid&63;
  const int quad = lane>>4, l16 = lane&15;
  const int wb_ = wave & 1;        // b-group (0: b 0-63, 1: b 64-127)
  const int wn_ = wave >> 1;       // n-group within block
  const int n0 = blockIdx.x*64;
  const int kz = blockIdx.y;
  const int n_wave = n0 + wn_*32;

  f32x4 acc[4][2];
  #pragma unroll
  for(int bt=0;bt<4;bt++)
    #pragma unroll
    for(int nt=0;nt<2;nt++) acc[bt][nt] = (f32x4){0.f,0.f,0.f,0.f};

  const size_t abase = (size_t)(wb_*64 + l16)*NITEMS + quad*8;
  const size_t wrow  = (size_t)(n_wave + l16)*NITEMS + quad*8;
  const int kbase = kz*(NITEMS/KC_);

  #pragma unroll 2
  for(int t=0; t<(NITEMS/KC_)/32; t++){
    const int k = kbase + t*32;
    bf16x8 ah[4], al[4];
    #pragma unroll
    for(int bt=0;bt<4;bt++){
      ah[bt] = *(const bf16x8*)(dvh + abase + (size_t)bt*16*NITEMS + k);
      al[bt] = *(const bf16x8*)(dvl + abase + (size_t)bt*16*NITEMS + k);
    }
    #pragma unroll
    for(int nt=0;nt<2;nt++){
      const float* wp = Wm + wrow + (size_t)nt*16*NITEMS + k;
      float4 wa = *(const float4*)wp;
      float4 wc = *(const float4*)(wp+4);
      float f[8] = {wa.x,wa.y,wa.z,wa.w,wc.x,wc.y,wc.z,wc.w};
      bf16x8 wh, wl;
      #pragma unroll
      for(int j=0;j<8;j++){
        u16 h = f2b(f[j]);
        wh[j] = (short)h;
        wl[j] = (short)f2b(f[j] - b2f(h));
      }
      #pragma unroll
      for(int bt=0;bt<4;bt++){
        acc[bt][nt] = __builtin_amdgcn_mfma_f32_16x16x32_bf16(ah[bt], wh, acc[bt][nt], 0,0,0);
        acc[bt][nt] = __builtin_amdgcn_mfma_f32_16x16x32_bf16(al[bt], wh, acc[bt][nt], 0,0,0);
        acc[bt][nt] = __builtin_amdgcn_mfma_f32_16x16x32_bf16(ah[bt], wl, acc[bt][nt], 0,0,0);
        acc[bt][nt] = __builtin_amdgcn_mfma_f32_16x16x32_bf16(al[bt], wl, acc[bt][nt], 0,0,0);
      }
    }
  }

  float* pp = part + (size_t)kz*NB*NITEMS;
  #pragma unroll
  for(int bt=0;bt<4;bt++){
    const int brow = wb_*64 + bt*16 + quad*4;
    #pragma unroll
    for(int nt=0;nt<2;nt++){
      const int n = n_wave + nt*16 + l16;
      #pragma unroll
      for(int i=0;i<4;i++)
        pp[(size_t)(brow+i)*NITEMS + n] = acc[bt][nt][i];
    }
  }
}

// out[b][n] = bias[n] + sum_kz part[kz][b][n]
__global__ __launch_bounds__(256) void k_opred(
    const float* __restrict__ part, const float* __restrict__ bias,
    float* __restrict__ out){
  const size_t i = ((size_t)blockIdx.x*256 + threadIdx.x)*4;
  float4 s = *(const float4*)&bias[(int)(i & (NITEMS-1))];
  #pragma unroll
  for(int kz=0;kz<KC_;kz++){
    float4 p = *(const float4*)&part[(size_t)kz*NB*NITEMS + i];
    s.x+=p.x; s.y+=p.y; s.z+=p.z; s.w+=p.w;
  }
  *(float4*)&out[i] = s;
}

// ------------------------------------------------- finalize scalars
__global__ void k_finalize(const float* __restrict__ loss, const int* __restrict__ counts,
                           float* __restrict__ out){
  __shared__ float sh[512];
  const int tid = threadIdx.x;
  float perp_sum = 0.f;
  for(int q=0;q<NQ_;q++){
    float avg = (float)counts[q*NEMB_+tid] / (float)NROWS;
    sh[tid] = avg*logf(avg + 1e-10f);
    __syncthreads();
    for(int s=256;s>0;s>>=1){ if(tid<s) sh[tid]+=sh[tid+s]; __syncthreads(); }
    if(tid==0) perp_sum += expf(-sh[0]);
    __syncthreads();
  }
  if(tid==0){
    float vl = 0.f;
    for(int q=0;q<NQ_;q++) vl += 1.25f*loss[q]/VQ_NELEM;
    out[0] = vl;
    out[1] = perp_sum/(float)NQ_;
  }
}

// =================================================================== launcher
extern "C" void kernel_launch(void* const* d_in, const int* in_sizes, int n_in,
                              void* d_out, int out_size, void* d_ws, size_t ws_size,
                              hipStream_t stream){
  (void)in_sizes; (void)n_in; (void)out_size;
  const int*   uid   = (const int*)d_in[0];
  const float* mat   = (const float*)d_in[1];
  const float* ec_w  = (const float*)d_in[2];
  const float* ec_b  = (const float*)d_in[3];
  const float* er_w1 = (const float*)d_in[4];
  const float* er_b1 = (const float*)d_in[5];
  const float* er_w2 = (const float*)d_in[6];
  const float* er_b2 = (const float*)d_in[7];
  const float* ef_w  = (const float*)d_in[8];
  const float* ef_b  = (const float*)d_in[9];
  const float* cb    = (const float*)d_in[10];
  const float* dt_w  = (const float*)d_in[11];
  const float* dt_b  = (const float*)d_in[12];
  const float* dr_w1 = (const float*)d_in[13];
  const float* dr_b1 = (const float*)d_in[14];
  const float* dr_w2 = (const float*)d_in[15];
  const float* dr_b2 = (const float*)d_in[16];
  const float* df_w  = (const float*)d_in[17];
  const float* df_b  = (const float*)d_in[18];
  const float* op_w  = (const float*)d_in[19];
  const float* op_b  = (const float*)d_in[20];
  float* outp = (float*)d_out;

  // ---------------- workspace: fixed region, then chunk buffers
  float* W = (float*)d_ws;
  size_t o = 0;
  float* xg    = W + o; o += (size_t)NB*NITEMS;
  float* dvec  = W + o; o += (size_t)NB*NITEMS;
  u16* wb3e0 = (u16*)(W + o); o += 3*NHID*NHID/2;
  u16* wb3e1 = (u16*)(W + o); o += 3*NHID*NHID/2;
  u16* wb3d0 = (u16*)(W + o); o += 3*NHID*NHID/2;
  u16* wb3d1 = (u16*)(W + o); o += 3*NHID*NHID/2;
  u16* wbF   = (u16*)(W + o); o += 3*NLAT*NHID/2;
  u16* wb1e0 = (u16*)(W + o); o += NHID*NHID/2;
  u16* wb1e1 = (u16*)(W + o); o += NHID*NHID/2;
  u16* wb1d0 = (u16*)(W + o); o += NHID*NHID/2;
  u16* wb1d1 = (u16*)(W + o); o += NHID*NHID/2;
  u16* wbT   = (u16*)(W + o); o += 4*NLAT*NHID/2;
  u16* cbh   = (u16*)(W + o); o += (size_t)NQ_*NEMB_*64/2;
  u16* cbl   = (u16*)(W + o); o += (size_t)NQ_*NEMB_*64/2;
  float* cb2   = W + o; o += NQ_*NEMB_;
  float* lossb = W + o; o += 4;
  int*   counts= (int*)(W + o); o += NQ_*NEMB_;
  u16* dvh   = (u16*)(W + o); o += (size_t)NB*NITEMS/2;
  u16* dvl   = (u16*)(W + o); o += (size_t)NB*NITEMS/2;
  float* partb = W + o; o += (size_t)KC_*NB*NITEMS;
  const size_t fixedF = o;

  // chunk buffers: two bf16 act buffers of CB*LDEC*NHID u16 each
  const size_t perBF = (size_t)LDEC*NHID/2;     // floats per batch elem per buffer
  size_t availF = ws_size/sizeof(float) > fixedF ? ws_size/sizeof(float) - fixedF : 0;
  int CB = 128;
  while(CB > 1 && (size_t)CB*2*perBF > availF) CB >>= 1;

  k_zero<<<(4 + NQ_*NEMB_ + 255)/256,256,0,stream>>>(lossb, 4 + NQ_*NEMB_);

  // weight packs (fp32 -> bf16, tap-major [k][co][ci])
  k_packw<<<(3*NHID*NHID+255)/256,256,0,stream>>>(er_w1,             wb3e0, NHID, NHID, 3);
  k_packw<<<(3*NHID*NHID+255)/256,256,0,stream>>>(er_w1+3*NHID*NHID, wb3e1, NHID, NHID, 3);
  k_packw<<<(3*NHID*NHID+255)/256,256,0,stream>>>(dr_w1,             wb3d0, NHID, NHID, 3);
  k_packw<<<(3*NHID*NHID+255)/256,256,0,stream>>>(dr_w1+3*NHID*NHID, wb3d1, NHID, NHID, 3);
  k_packw<<<(3*NLAT*NHID+255)/256,256,0,stream>>>(ef_w,              wbF,   NLAT, NHID, 3);
  k_packw<<<(NHID*NHID+255)/256,256,0,stream>>>(er_w2,               wb1e0, NHID, NHID, 1);
  k_packw<<<(NHID*NHID+255)/256,256,0,stream>>>(er_w2+NHID*NHID,     wb1e1, NHID, NHID, 1);
  k_packw<<<(NHID*NHID+255)/256,256,0,stream>>>(dr_w2,               wb1d0, NHID, NHID, 1);
  k_packw<<<(NHID*NHID+255)/256,256,0,stream>>>(dr_w2+NHID*NHID,     wb1d1, NHID, NHID, 1);
  k_packwT<<<(4*NLAT*NHID+255)/256,256,0,stream>>>(dt_w, wbT);
  k_cbsplit<<<(NQ_*NEMB_*64)/256,256,0,stream>>>(cb, cbh, cbl);
  k_cbnorm<<<(NQ_*NEMB_+255)/256,256,0,stream>>>(cb, cb2);

  k_gather<<<dim3(NITEMS/256, NB),256,0,stream>>>(uid, mat, xg);

  u16* D0b = (u16*)(W + fixedF);
  u16* D1b = D0b + (size_t)CB*LDEC*NHID;

  for(int c0 = 0; c0 < NB; c0 += CB){
    u16* E0 = D0b;                                  // [CB][4096][256] bf16
    u16* E1 = D0b + (size_t)CB*LENC*NHID;
    float* z_e = (float*)D1b;                       // [CB][64][4096] f32
    float* z_q = z_e + (size_t)CB*NLAT*LENC;
    const float* xgc = xg + (size_t)c0*NITEMS;
    float* dvc = dvec + (size_t)c0*NITEMS;

    // ---- encoder
    k_enc0<<<dim3(LENC/16, CB),256,0,stream>>>(xgc, ec_w, ec_b, E0);
    k_cgemm<256,256,3,2,2,1,0,0><<<dim3(LENC/128, 2, CB),256,0,stream>>>(E0, wb3e0, er_b1,      nullptr, E1, LENC);
    k_cgemm<256,256,1,2,2,1,1,0><<<dim3(LENC/128, 2, CB),256,0,stream>>>(E1, wb1e0, er_b2,      E0,      E0, LENC);
    k_cgemm<256,256,3,2,2,1,0,0><<<dim3(LENC/128, 2, CB),256,0,stream>>>(E0, wb3e1, er_b1+NHID, nullptr, E1, LENC);
    k_cgemm<256,256,1,2,2,1,1,0><<<dim3(LENC/128, 2, CB),256,0,stream>>>(E1, wb1e1, er_b2+NHID, E0,      E0, LENC);
    k_cgemm<256, 64,3,1,4,0,0,1><<<dim3(LENC/256, 1, CB),256,0,stream>>>(E0, wbF,   ef_b,       nullptr, z_e, LENC);

    // ---- residual VQ (MFMA split-bf16): 256 rows/block, 64 rows/wave
    k_vq<<<CB*16,256,0,stream>>>(z_e, cb, cbh, cbl, cb2, z_q, lossb, counts);

    // ---- decoder
    k_convT<<<dim3(LENC/64, 2, CB),256,0,stream>>>(z_q, wbT, dt_b, D0b);
    k_cgemm<256,256,3,2,2,1,0,0><<<dim3(LDEC/128, 2, CB),256,0,stream>>>(D0b, wb3d0, dr_b1,      nullptr, D1b, LDEC);
    k_cgemm<256,256,1,2,2,1,1,0><<<dim3(LDEC/128, 2, CB),256,0,stream>>>(D1b, wb1d0, dr_b2,      D0b,     D0b, LDEC);
    k_cgemm<256,256,3,2,2,1,0,0><<<dim3(LDEC/128, 2, CB),256,0,stream>>>(D0b, wb3d1, dr_b1+NHID, nullptr, D1b, LDEC);
    k_cgemm<256,256,1,2,2,1,1,0><<<dim3(LDEC/128, 2, CB),256,0,stream>>>(D1b, wb1d1, dr_b2+NHID, D0b,     D0b, LDEC);
    k_finalT<<<dim3(LDEC/64, CB),256,0,stream>>>(D0b, df_w, df_b, dvc);
  }

  // ---- head: recon = dvec @ W^T + b  (MFMA split-bf16, K-chunked partials)
  k_packdv<<<NB*NITEMS/256,256,0,stream>>>(dvec, dvh, dvl);
  k_opmm<<<dim3(NITEMS/64, KC_),256,0,stream>>>(dvh, dvl, op_w, partb);
  k_opred<<<NB*NITEMS/1024,256,0,stream>>>(partb, op_b, outp);
  k_finalize<<<1,512,0,stream>>>(lossb, counts, outp + (size_t)NB*NITEMS);
}